// Round 1
// baseline (539.206 us; speedup 1.0000x reference)
//
#include <hip/hip_runtime.h>

// GAT conv forward: N=100000 nodes, E=1.6M edges (+N self loops), IN_F=128,
// OUT_F=32, HEADS=4. Pipeline:
//   1. k_init_deg/k_hist/scan/k_scatter: build CSR grouped by dst (self loops appended)
//   2. k_gemm_att: h = x@W [N,128] fp32 tiled GEMM; epilogue computes
//      a_src[n,h]=<h[n,h,:],att_src[h]>, a_dst likewise (shfl-reduce over 8 lanes)
//   3. k_aggregate: one wave per dst node; unnormalized online softmax
//      (no segment-max needed: |e| <~ 14 so exp() is fp32-safe), zero atomics.

#define NEG_SLOPE 0.2f

__global__ void k_init_deg(int* __restrict__ cur, int Nn) {
  int i = blockIdx.x * blockDim.x + threadIdx.x;
  if (i < Nn) cur[i] = 1;  // self loop
}

__global__ void k_hist(const int* __restrict__ ei, int* __restrict__ cur, int E) {
  int i = blockIdx.x * blockDim.x + threadIdx.x;
  if (i < E) atomicAdd(&cur[ei[E + i]], 1);  // dst = edge_index[1][i]
}

// block sums over 2048-element chunks
__global__ void k_scan1(const int* __restrict__ cur, int* __restrict__ partial, int Nn) {
  __shared__ int wsum[4];
  int t = threadIdx.x;
  int base = blockIdx.x * 2048 + t * 8;
  int sum = 0;
#pragma unroll
  for (int j = 0; j < 8; ++j) { int i = base + j; if (i < Nn) sum += cur[i]; }
  int lane = t & 63, w = t >> 6;
#pragma unroll
  for (int d = 32; d >= 1; d >>= 1) sum += __shfl_down(sum, d, 64);
  if (lane == 0) wsum[w] = sum;
  __syncthreads();
  if (t == 0) partial[blockIdx.x] = wsum[0] + wsum[1] + wsum[2] + wsum[3];
}

// serial exclusive scan of ~49 block partials + write off[N]
__global__ void k_scan2(int* __restrict__ partial, int* __restrict__ off, int B1, int total, int Nn) {
  if (threadIdx.x == 0) {
    int acc = 0;
    for (int i = 0; i < B1; ++i) { int v = partial[i]; partial[i] = acc; acc += v; }
    off[Nn] = total;
  }
}

// per-chunk exclusive scan + chunk base -> off[i]; cur[i] = off[i] (scatter cursor)
__global__ void k_scan3(int* __restrict__ cur, int* __restrict__ off, const int* __restrict__ partial, int Nn) {
  __shared__ int wsum[4];
  int t = threadIdx.x;
  int idx0 = blockIdx.x * 2048 + t * 8;
  int d[8], loc[8];
#pragma unroll
  for (int j = 0; j < 8; ++j) d[j] = (idx0 + j < Nn) ? cur[idx0 + j] : 0;
  int s = 0;
#pragma unroll
  for (int j = 0; j < 8; ++j) { loc[j] = s; s += d[j]; }
  int lane = t & 63, w = t >> 6;
  int inc = s;
#pragma unroll
  for (int delta = 1; delta < 64; delta <<= 1) {
    int v = __shfl_up(inc, delta, 64);
    if (lane >= delta) inc += v;
  }
  if (lane == 63) wsum[w] = inc;
  __syncthreads();
  int wbase = 0;
  for (int ww = 0; ww < w; ++ww) wbase += wsum[ww];
  int tbase = partial[blockIdx.x] + wbase + (inc - s);
#pragma unroll
  for (int j = 0; j < 8; ++j) {
    int i = idx0 + j;
    if (i < Nn) { int v = tbase + loc[j]; off[i] = v; cur[i] = v; }
  }
}

__global__ void k_scatter(const int* __restrict__ ei, int* __restrict__ cur,
                          int* __restrict__ ssrc, int E, int Nn) {
  int i = blockIdx.x * blockDim.x + threadIdx.x;
  if (i >= E + Nn) return;
  int s, dn;
  if (i < E) { s = ei[i]; dn = ei[E + i]; }
  else       { s = i - E; dn = s; }            // self loop
  int pos = atomicAdd(&cur[dn], 1);
  ssrc[pos] = s;
}

// h = x @ W  (64 rows x 128 cols per block, K=128 in chunks of 16)
// epilogue: a_src/a_dst via per-thread 4-col dot + shfl-reduce over 8 lanes/head
__global__ __launch_bounds__(256) void k_gemm_att(
    const float* __restrict__ x, const float* __restrict__ W,
    const float* __restrict__ attS, const float* __restrict__ attD,
    float* __restrict__ h, float* __restrict__ aS, float* __restrict__ aD, int Nn) {
  __shared__ float xs[64 * 16];
  __shared__ float ws[16 * 128];
  int tid = threadIdx.x;
  int tx = tid & 31, ty = tid >> 5;
  int node0 = blockIdx.x * 64;
  int col0 = tx * 4;
  float acc[8][4] = {};
  float4 atS = ((const float4*)attS)[tx];
  float4 atD = ((const float4*)attD)[tx];

  for (int k0 = 0; k0 < 128; k0 += 16) {
    // stage x tile: one float4 per thread
    {
      int row = tid >> 2;
      int kk = (tid & 3) * 4;
      int gr = node0 + row; if (gr >= Nn) gr = Nn - 1;
      *(float4*)(xs + row * 16 + kk) = *(const float4*)(x + gr * 128 + k0 + kk);
    }
    // stage W chunk: two float4 per thread
#pragma unroll
    for (int i = 0; i < 2; ++i) {
      int f4 = tid + i * 256;
      int kw = f4 >> 5;
      int cw = (f4 & 31) * 4;
      *(float4*)(ws + kw * 128 + cw) = *(const float4*)(W + (size_t)(k0 + kw) * 128 + cw);
    }
    __syncthreads();
#pragma unroll
    for (int k = 0; k < 16; ++k) {
      float4 b = *(const float4*)(ws + k * 128 + col0);
#pragma unroll
      for (int rr = 0; rr < 8; ++rr) {
        float a = xs[(ty * 8 + rr) * 16 + k];
        acc[rr][0] += a * b.x; acc[rr][1] += a * b.y;
        acc[rr][2] += a * b.z; acc[rr][3] += a * b.w;
      }
    }
    __syncthreads();
  }

  int hgrp = tx >> 3;  // head owned by this 8-lane group
#pragma unroll
  for (int rr = 0; rr < 8; ++rr) {
    int row = node0 + ty * 8 + rr;
    float pS = acc[rr][0] * atS.x + acc[rr][1] * atS.y + acc[rr][2] * atS.z + acc[rr][3] * atS.w;
    float pD = acc[rr][0] * atD.x + acc[rr][1] * atD.y + acc[rr][2] * atD.z + acc[rr][3] * atD.w;
    pS += __shfl_down(pS, 4, 8); pS += __shfl_down(pS, 2, 8); pS += __shfl_down(pS, 1, 8);
    pD += __shfl_down(pD, 4, 8); pD += __shfl_down(pD, 2, 8); pD += __shfl_down(pD, 1, 8);
    if (row < Nn) {
      *(float4*)(h + (size_t)row * 128 + col0) =
          make_float4(acc[rr][0], acc[rr][1], acc[rr][2], acc[rr][3]);
      if ((tx & 7) == 0) {
        aS[row * 4 + hgrp] = pS;
        aD[row * 4 + hgrp] = pD;
      }
    }
  }
}

// one wave per dst node; lane l owns output floats [2l, 2l+1] (head = l/16)
__global__ __launch_bounds__(256) void k_aggregate(
    const float* __restrict__ h, const float* __restrict__ aS, const float* __restrict__ aD,
    const int* __restrict__ off, const int* __restrict__ ssrc,
    const float* __restrict__ bias, float* __restrict__ out, int Nn) {
  int wave = threadIdx.x >> 6;
  int lane = threadIdx.x & 63;
  int node = blockIdx.x * 4 + wave;
  if (node >= Nn) return;
  int hd = lane >> 4;
  float ad = aD[node * 4 + hd];
  int p0 = off[node], p1 = off[node + 1];
  const float2* h2 = (const float2*)h;
  float accx = 0.f, accy = 0.f, den = 0.f;
  for (int p = p0; p < p1; ++p) {
    int src = ssrc[p];
    float e = aS[src * 4 + hd] + ad;
    e = e > 0.f ? e : NEG_SLOPE * e;
    float ex = __expf(e);
    float2 hv = h2[(size_t)src * 64 + lane];
    accx += ex * hv.x;
    accy += ex * hv.y;
    den += ex;
  }
  float inv = 1.0f / (den + 1e-16f);
  float2 bv = ((const float2*)bias)[lane];
  float2 o;
  o.x = accx * inv + bv.x;
  o.y = accy * inv + bv.y;
  ((float2*)out)[(size_t)node * 64 + lane] = o;
}

extern "C" void kernel_launch(void* const* d_in, const int* in_sizes, int n_in,
                              void* d_out, int out_size, void* d_ws, size_t ws_size,
                              hipStream_t stream) {
  const float* x    = (const float*)d_in[0];
  const int*   ei   = (const int*)d_in[1];
  const float* W    = (const float*)d_in[2];
  const float* attS = (const float*)d_in[3];
  const float* attD = (const float*)d_in[4];
  const float* bias = (const float*)d_in[5];
  float* out = (float*)d_out;

  const int Nn = in_sizes[0] / 128;
  const int E  = in_sizes[1] / 2;
  const int B1 = (Nn + 2047) / 2048;

  // workspace layout (16-element aligned)
  char* ws = (char*)d_ws;
  size_t o = 0;
  auto take = [&](size_t bytes) { void* p = ws + o; o += (bytes + 255) & ~(size_t)255; return p; };
  int*   off     = (int*)take((size_t)(Nn + 1) * 4);
  int*   cur     = (int*)take((size_t)Nn * 4);
  int*   ssrc    = (int*)take((size_t)(E + Nn) * 4);
  int*   partial = (int*)take((size_t)(B1 + 1) * 4);
  float* aS      = (float*)take((size_t)Nn * 4 * 4);
  float* aD      = (float*)take((size_t)Nn * 4 * 4);
  float* h       = (float*)take((size_t)Nn * 128 * 4);
  (void)ws_size; (void)o;

  k_init_deg<<<(Nn + 255) / 256, 256, 0, stream>>>(cur, Nn);
  k_hist<<<(E + 255) / 256, 256, 0, stream>>>(ei, cur, E);
  k_scan1<<<B1, 256, 0, stream>>>(cur, partial, Nn);
  k_scan2<<<1, 64, 0, stream>>>(partial, off, B1, E + Nn, Nn);
  k_scan3<<<B1, 256, 0, stream>>>(cur, off, partial, Nn);
  k_scatter<<<(E + Nn + 255) / 256, 256, 0, stream>>>(ei, cur, ssrc, E, Nn);
  k_gemm_att<<<(Nn + 63) / 64, 256, 0, stream>>>(x, W, attS, attD, h, aS, aD, Nn);
  k_aggregate<<<(Nn + 3) / 4, 256, 0, stream>>>(h, aS, aD, off, ssrc, bias, out, Nn);
}

// Round 2
// 430.420 us; speedup vs baseline: 1.2527x; 1.2527x over previous
//
#include <hip/hip_runtime.h>

// GAT conv forward: N=100000 nodes, E=1.6M edges (+N self loops), IN_F=128,
// OUT_F=32, HEADS=4. Pipeline:
//   1. k_init_deg/k_hist/scan/k_scatter: build CSR grouped by dst (self loops appended)
//   2. k_gemm_att: h = x@W [N,128] fp32 tiled GEMM; epilogue computes
//      a_src[n,h]=<h[n,h,:],att_src[h]>, a_dst likewise (shfl-reduce over 8 lanes),
//      stores h as PACKED BF16 pairs (halves the aggregate gather traffic).
//   3. k_aggregate: one wave per dst node; unnormalized softmax (|e| small so
//      exp() fp32-safe), zero atomics; degree loop unrolled x4 with index
//      prefetch for memory-level parallelism (R1 showed VGPR=12, latency-bound).

#define NEG_SLOPE 0.2f

__device__ __forceinline__ unsigned int f2bf_pack(float a, float b) {
  unsigned ua = __float_as_uint(a);
  unsigned ub = __float_as_uint(b);
  unsigned ra = (ua + 0x7fffu + ((ua >> 16) & 1u)) >> 16;   // RNE
  unsigned rb = (ub + 0x7fffu + ((ub >> 16) & 1u)) >> 16;
  return (rb << 16) | (ra & 0xffffu);
}

__global__ void k_init_deg(int* __restrict__ cur, int Nn) {
  int i = blockIdx.x * blockDim.x + threadIdx.x;
  if (i < Nn) cur[i] = 1;  // self loop
}

__global__ void k_hist(const int* __restrict__ ei, int* __restrict__ cur, int E) {
  int i = blockIdx.x * blockDim.x + threadIdx.x;
  if (i < E) atomicAdd(&cur[ei[E + i]], 1);  // dst = edge_index[1][i]
}

// block sums over 2048-element chunks
__global__ void k_scan1(const int* __restrict__ cur, int* __restrict__ partial, int Nn) {
  __shared__ int wsum[4];
  int t = threadIdx.x;
  int base = blockIdx.x * 2048 + t * 8;
  int sum = 0;
#pragma unroll
  for (int j = 0; j < 8; ++j) { int i = base + j; if (i < Nn) sum += cur[i]; }
  int lane = t & 63, w = t >> 6;
#pragma unroll
  for (int d = 32; d >= 1; d >>= 1) sum += __shfl_down(sum, d, 64);
  if (lane == 0) wsum[w] = sum;
  __syncthreads();
  if (t == 0) partial[blockIdx.x] = wsum[0] + wsum[1] + wsum[2] + wsum[3];
}

// serial exclusive scan of ~49 block partials + write off[N]
__global__ void k_scan2(int* __restrict__ partial, int* __restrict__ off, int B1, int total, int Nn) {
  if (threadIdx.x == 0) {
    int acc = 0;
    for (int i = 0; i < B1; ++i) { int v = partial[i]; partial[i] = acc; acc += v; }
    off[Nn] = total;
  }
}

// per-chunk exclusive scan + chunk base -> off[i]; cur[i] = off[i] (scatter cursor)
__global__ void k_scan3(int* __restrict__ cur, int* __restrict__ off, const int* __restrict__ partial, int Nn) {
  __shared__ int wsum[4];
  int t = threadIdx.x;
  int idx0 = blockIdx.x * 2048 + t * 8;
  int d[8], loc[8];
#pragma unroll
  for (int j = 0; j < 8; ++j) d[j] = (idx0 + j < Nn) ? cur[idx0 + j] : 0;
  int s = 0;
#pragma unroll
  for (int j = 0; j < 8; ++j) { loc[j] = s; s += d[j]; }
  int lane = t & 63, w = t >> 6;
  int inc = s;
#pragma unroll
  for (int delta = 1; delta < 64; delta <<= 1) {
    int v = __shfl_up(inc, delta, 64);
    if (lane >= delta) inc += v;
  }
  if (lane == 63) wsum[w] = inc;
  __syncthreads();
  int wbase = 0;
  for (int ww = 0; ww < w; ++ww) wbase += wsum[ww];
  int tbase = partial[blockIdx.x] + wbase + (inc - s);
#pragma unroll
  for (int j = 0; j < 8; ++j) {
    int i = idx0 + j;
    if (i < Nn) { int v = tbase + loc[j]; off[i] = v; cur[i] = v; }
  }
}

__global__ void k_scatter(const int* __restrict__ ei, int* __restrict__ cur,
                          int* __restrict__ ssrc, int E, int Nn) {
  int i = blockIdx.x * blockDim.x + threadIdx.x;
  if (i >= E + Nn) return;
  int s, dn;
  if (i < E) { s = ei[i]; dn = ei[E + i]; }
  else       { s = i - E; dn = s; }            // self loop
  int pos = atomicAdd(&cur[dn], 1);
  ssrc[pos] = s;
}

// h = x @ W  (64 rows x 128 cols per block, K=128 in chunks of 16)
// epilogue: a_src/a_dst via per-thread 4-col dot + shfl-reduce over 8 lanes/head;
// h stored as packed bf16 pairs (uint per pair), layout [N][64] uints.
__global__ __launch_bounds__(256) void k_gemm_att(
    const float* __restrict__ x, const float* __restrict__ W,
    const float* __restrict__ attS, const float* __restrict__ attD,
    unsigned int* __restrict__ hb, float* __restrict__ aS, float* __restrict__ aD, int Nn) {
  __shared__ float xs[64 * 16];
  __shared__ float ws[16 * 128];
  int tid = threadIdx.x;
  int tx = tid & 31, ty = tid >> 5;
  int node0 = blockIdx.x * 64;
  int col0 = tx * 4;
  float acc[8][4] = {};
  float4 atS = ((const float4*)attS)[tx];
  float4 atD = ((const float4*)attD)[tx];

  for (int k0 = 0; k0 < 128; k0 += 16) {
    // stage x tile: one float4 per thread
    {
      int row = tid >> 2;
      int kk = (tid & 3) * 4;
      int gr = node0 + row; if (gr >= Nn) gr = Nn - 1;
      *(float4*)(xs + row * 16 + kk) = *(const float4*)(x + gr * 128 + k0 + kk);
    }
    // stage W chunk: two float4 per thread
#pragma unroll
    for (int i = 0; i < 2; ++i) {
      int f4 = tid + i * 256;
      int kw = f4 >> 5;
      int cw = (f4 & 31) * 4;
      *(float4*)(ws + kw * 128 + cw) = *(const float4*)(W + (size_t)(k0 + kw) * 128 + cw);
    }
    __syncthreads();
#pragma unroll
    for (int k = 0; k < 16; ++k) {
      float4 b = *(const float4*)(ws + k * 128 + col0);
#pragma unroll
      for (int rr = 0; rr < 8; ++rr) {
        float a = xs[(ty * 8 + rr) * 16 + k];
        acc[rr][0] += a * b.x; acc[rr][1] += a * b.y;
        acc[rr][2] += a * b.z; acc[rr][3] += a * b.w;
      }
    }
    __syncthreads();
  }

  int hgrp = tx >> 3;  // head owned by this 8-lane group
#pragma unroll
  for (int rr = 0; rr < 8; ++rr) {
    int row = node0 + ty * 8 + rr;
    float pS = acc[rr][0] * atS.x + acc[rr][1] * atS.y + acc[rr][2] * atS.z + acc[rr][3] * atS.w;
    float pD = acc[rr][0] * atD.x + acc[rr][1] * atD.y + acc[rr][2] * atD.z + acc[rr][3] * atD.w;
    pS += __shfl_down(pS, 4, 8); pS += __shfl_down(pS, 2, 8); pS += __shfl_down(pS, 1, 8);
    pD += __shfl_down(pD, 4, 8); pD += __shfl_down(pD, 2, 8); pD += __shfl_down(pD, 1, 8);
    if (row < Nn) {
      uint2 pk;
      pk.x = f2bf_pack(acc[rr][0], acc[rr][1]);
      pk.y = f2bf_pack(acc[rr][2], acc[rr][3]);
      *(uint2*)(hb + (size_t)row * 64 + tx * 2) = pk;
      if ((tx & 7) == 0) {
        aS[row * 4 + hgrp] = pS;
        aD[row * 4 + hgrp] = pD;
      }
    }
  }
}

// one wave per dst node; lane l owns output floats [2l, 2l+1] (head = l/16).
// Degree loop unrolled x4 with next-chunk index prefetch: 4 independent
// 256B h-gathers in flight per wave instead of 1 (R1: VGPR=12, latency-bound).
__global__ __launch_bounds__(256) void k_aggregate(
    const unsigned int* __restrict__ hb, const float* __restrict__ aS, const float* __restrict__ aD,
    const int* __restrict__ off, const int* __restrict__ ssrc,
    const float* __restrict__ bias, float* __restrict__ out, int Nn) {
  int wave = threadIdx.x >> 6;
  int lane = threadIdx.x & 63;
  int node = blockIdx.x * 4 + wave;
  if (node >= Nn) return;
  int hd = lane >> 4;
  float ad = aD[node * 4 + hd];
  int p0 = off[node], p1 = off[node + 1];
  float accx = 0.f, accy = 0.f, den = 0.f;
  int deg = p1 - p0;
  int nch = deg >> 2;
  const int* sp = ssrc + p0;
  int s0 = 0, s1 = 0, s2 = 0, s3 = 0;
  if (nch > 0) { s0 = sp[0]; s1 = sp[1]; s2 = sp[2]; s3 = sp[3]; }
  for (int c = 0; c < nch; ++c) {
    // issue 4 independent gathers + 4 attention loads for current chunk
    unsigned int v0 = hb[(size_t)s0 * 64 + lane];
    unsigned int v1 = hb[(size_t)s1 * 64 + lane];
    unsigned int v2 = hb[(size_t)s2 * 64 + lane];
    unsigned int v3 = hb[(size_t)s3 * 64 + lane];
    float e0 = aS[s0 * 4 + hd] + ad;
    float e1 = aS[s1 * 4 + hd] + ad;
    float e2 = aS[s2 * 4 + hd] + ad;
    float e3 = aS[s3 * 4 + hd] + ad;
    // prefetch next chunk's indices while the above are in flight
    int t0 = 0, t1 = 0, t2 = 0, t3 = 0;
    if (c + 1 < nch) {
      const int* np = sp + 4;
      t0 = np[0]; t1 = np[1]; t2 = np[2]; t3 = np[3];
    }
    e0 = e0 > 0.f ? e0 : NEG_SLOPE * e0;
    e1 = e1 > 0.f ? e1 : NEG_SLOPE * e1;
    e2 = e2 > 0.f ? e2 : NEG_SLOPE * e2;
    e3 = e3 > 0.f ? e3 : NEG_SLOPE * e3;
    float ex0 = __expf(e0), ex1 = __expf(e1), ex2 = __expf(e2), ex3 = __expf(e3);
    den += ((ex0 + ex1) + (ex2 + ex3));
    accx += ex0 * __uint_as_float(v0 << 16);
    accy += ex0 * __uint_as_float(v0 & 0xffff0000u);
    accx += ex1 * __uint_as_float(v1 << 16);
    accy += ex1 * __uint_as_float(v1 & 0xffff0000u);
    accx += ex2 * __uint_as_float(v2 << 16);
    accy += ex2 * __uint_as_float(v2 & 0xffff0000u);
    accx += ex3 * __uint_as_float(v3 << 16);
    accy += ex3 * __uint_as_float(v3 & 0xffff0000u);
    s0 = t0; s1 = t1; s2 = t2; s3 = t3;
    sp += 4;
  }
  // tail (<4 edges)
  for (int p = p0 + (nch << 2); p < p1; ++p) {
    int src = ssrc[p];
    float e = aS[src * 4 + hd] + ad;
    e = e > 0.f ? e : NEG_SLOPE * e;
    float ex = __expf(e);
    unsigned int v = hb[(size_t)src * 64 + lane];
    accx += ex * __uint_as_float(v << 16);
    accy += ex * __uint_as_float(v & 0xffff0000u);
    den += ex;
  }
  float inv = 1.0f / (den + 1e-16f);
  float2 bv = ((const float2*)bias)[lane];
  float2 o;
  o.x = accx * inv + bv.x;
  o.y = accy * inv + bv.y;
  ((float2*)out)[(size_t)node * 64 + lane] = o;
}

extern "C" void kernel_launch(void* const* d_in, const int* in_sizes, int n_in,
                              void* d_out, int out_size, void* d_ws, size_t ws_size,
                              hipStream_t stream) {
  const float* x    = (const float*)d_in[0];
  const int*   ei   = (const int*)d_in[1];
  const float* W    = (const float*)d_in[2];
  const float* attS = (const float*)d_in[3];
  const float* attD = (const float*)d_in[4];
  const float* bias = (const float*)d_in[5];
  float* out = (float*)d_out;

  const int Nn = in_sizes[0] / 128;
  const int E  = in_sizes[1] / 2;
  const int B1 = (Nn + 2047) / 2048;

  // workspace layout (256B aligned)
  char* ws = (char*)d_ws;
  size_t o = 0;
  auto take = [&](size_t bytes) { void* p = ws + o; o += (bytes + 255) & ~(size_t)255; return p; };
  int*   off     = (int*)take((size_t)(Nn + 1) * 4);
  int*   cur     = (int*)take((size_t)Nn * 4);
  int*   ssrc    = (int*)take((size_t)(E + Nn) * 4);
  int*   partial = (int*)take((size_t)(B1 + 1) * 4);
  float* aS      = (float*)take((size_t)Nn * 4 * 4);
  float* aD      = (float*)take((size_t)Nn * 4 * 4);
  unsigned int* hb = (unsigned int*)take((size_t)Nn * 64 * 4);  // bf16-packed h
  (void)ws_size; (void)o;

  k_init_deg<<<(Nn + 255) / 256, 256, 0, stream>>>(cur, Nn);
  k_hist<<<(E + 255) / 256, 256, 0, stream>>>(ei, cur, E);
  k_scan1<<<B1, 256, 0, stream>>>(cur, partial, Nn);
  k_scan2<<<1, 64, 0, stream>>>(partial, off, B1, E + Nn, Nn);
  k_scan3<<<B1, 256, 0, stream>>>(cur, off, partial, Nn);
  k_scatter<<<(E + Nn + 255) / 256, 256, 0, stream>>>(ei, cur, ssrc, E, Nn);
  k_gemm_att<<<(Nn + 63) / 64, 256, 0, stream>>>(x, W, attS, attD, hb, aS, aD, Nn);
  k_aggregate<<<(Nn + 3) / 4, 256, 0, stream>>>(hb, aS, aD, off, ssrc, bias, out, Nn);
}

// Round 3
// 374.678 us; speedup vs baseline: 1.4391x; 1.1488x over previous
//
#include <hip/hip_runtime.h>

// GAT conv forward: N=100000 nodes, E=1.6M edges (+N self loops), IN_F=128,
// OUT_F=32, HEADS=4. Pipeline:
//   1. k_init_deg/k_hist/scans: per-dst degree histogram + CSR offsets
//   2. k_bin + k_scatter2: dst-binned two-pass CSR build. R2 showed the naive
//      scatter at 137us, WRITE_SIZE=108MB (1.7M random 4B stores -> 64B line
//      each, ~13% HBM efficiency). Binning by dst>>9 makes pass-2 writes land
//      in a 35KB L2-resident window per bucket.
//   3. k_gemm_att: h = x@W fp32 tiled GEMM; epilogue computes a_src/a_dst and
//      stores h as packed bf16 pairs (halves aggregate gather traffic).
//   4. k_aggregate: one wave per dst node; unnormalized softmax, zero atomics,
//      degree loop unrolled x4 with index prefetch.

#define NEG_SLOPE 0.2f
#define NB_MAX 256      // max buckets (supports Nn <= 131072)
#define BSHIFT 9        // 512 nodes per bucket
#define CHUNK 4096      // edges per k_bin block

__device__ __forceinline__ unsigned int f2bf_pack(float a, float b) {
  unsigned ua = __float_as_uint(a);
  unsigned ub = __float_as_uint(b);
  unsigned ra = (ua + 0x7fffu + ((ua >> 16) & 1u)) >> 16;   // RNE
  unsigned rb = (ub + 0x7fffu + ((ub >> 16) & 1u)) >> 16;
  return (rb << 16) | (ra & 0xffffu);
}

__global__ void k_init_deg(int* __restrict__ cur, int Nn) {
  int i = blockIdx.x * blockDim.x + threadIdx.x;
  if (i < Nn) cur[i] = 1;  // self loop
}

__global__ void k_hist(const int* __restrict__ ei, int* __restrict__ cur, int E) {
  int i = blockIdx.x * blockDim.x + threadIdx.x;
  if (i < E) atomicAdd(&cur[ei[E + i]], 1);  // dst = edge_index[1][i]
}

// block sums over 2048-element chunks
__global__ void k_scan1(const int* __restrict__ cur, int* __restrict__ partial, int Nn) {
  __shared__ int wsum[4];
  int t = threadIdx.x;
  int base = blockIdx.x * 2048 + t * 8;
  int sum = 0;
#pragma unroll
  for (int j = 0; j < 8; ++j) { int i = base + j; if (i < Nn) sum += cur[i]; }
  int lane = t & 63, w = t >> 6;
#pragma unroll
  for (int d = 32; d >= 1; d >>= 1) sum += __shfl_down(sum, d, 64);
  if (lane == 0) wsum[w] = sum;
  __syncthreads();
  if (t == 0) partial[blockIdx.x] = wsum[0] + wsum[1] + wsum[2] + wsum[3];
}

// serial exclusive scan of ~49 block partials + write off[N]
__global__ void k_scan2(int* __restrict__ partial, int* __restrict__ off, int B1, int total, int Nn) {
  if (threadIdx.x == 0) {
    int acc = 0;
    for (int i = 0; i < B1; ++i) { int v = partial[i]; partial[i] = acc; acc += v; }
    off[Nn] = total;
  }
}

// per-chunk exclusive scan + chunk base -> off[i]; cur[i] = off[i] (scatter cursor)
__global__ void k_scan3(int* __restrict__ cur, int* __restrict__ off, const int* __restrict__ partial, int Nn) {
  __shared__ int wsum[4];
  int t = threadIdx.x;
  int idx0 = blockIdx.x * 2048 + t * 8;
  int d[8], loc[8];
#pragma unroll
  for (int j = 0; j < 8; ++j) d[j] = (idx0 + j < Nn) ? cur[idx0 + j] : 0;
  int s = 0;
#pragma unroll
  for (int j = 0; j < 8; ++j) { loc[j] = s; s += d[j]; }
  int lane = t & 63, w = t >> 6;
  int inc = s;
#pragma unroll
  for (int delta = 1; delta < 64; delta <<= 1) {
    int v = __shfl_up(inc, delta, 64);
    if (lane >= delta) inc += v;
  }
  if (lane == 63) wsum[w] = inc;
  __syncthreads();
  int wbase = 0;
  for (int ww = 0; ww < w; ++ww) wbase += wsum[ww];
  int tbase = partial[blockIdx.x] + wbase + (inc - s);
#pragma unroll
  for (int j = 0; j < 8; ++j) {
    int i = idx0 + j;
    if (i < Nn) { int v = tbase + loc[j]; off[i] = v; cur[i] = v; }
  }
}

// bucket cursors: bucket b's binned region starts at off[b*512]
__global__ void k_bcur_init(const int* __restrict__ off, int* __restrict__ bcur, int nb) {
  int b = blockIdx.x * blockDim.x + threadIdx.x;
  if (b < nb) bcur[b] = off[b << BSHIFT];
}

// Pass A: bin (src,dst) pairs by dst>>9 into per-bucket regions of `binned`.
// Per block: LDS histogram + rank -> wave scan -> local reorder in LDS ->
// global cursor reservation -> coalesced run flush.
__global__ __launch_bounds__(256) void k_bin(
    const int* __restrict__ ei, int* __restrict__ bcur,
    uint2* __restrict__ binned, int E, int nb) {
  __shared__ uint2 buf[CHUNK];          // 32 KB reordered pairs
  __shared__ int hist[NB_MAX];          // per-bucket counts
  __shared__ int loc[NB_MAX];           // exclusive prefix of hist
  __shared__ int gbase[NB_MAX];         // global base reserved for this block
  int tid = threadIdx.x;
  int e0 = blockIdx.x * CHUNK;
  int n = E - e0; if (n > CHUNK) n = CHUNK;

  for (int i = tid; i < NB_MAX; i += 256) hist[i] = 0;
  __syncthreads();

  // phase 1: count + per-(block,bucket) rank
  int dstv[CHUNK / 256];
  int rankv[CHUNK / 256];
#pragma unroll
  for (int j = 0; j < CHUNK / 256; ++j) {
    int idx = j * 256 + tid;
    dstv[j] = -1;
    if (idx < n) {
      int d = ei[E + e0 + idx];
      dstv[j] = d;
      rankv[j] = atomicAdd(&hist[d >> BSHIFT], 1);
    }
  }
  __syncthreads();

  // phase 2: exclusive scan of hist[0..255] (wave 0; 4 buckets/lane)
  if (tid < 64) {
    int base = tid * 4;
    int v0 = hist[base], v1 = hist[base + 1], v2 = hist[base + 2], v3 = hist[base + 3];
    int s = v0 + v1 + v2 + v3;
    int inc = s;
#pragma unroll
    for (int d = 1; d < 64; d <<= 1) {
      int t = __shfl_up(inc, d, 64);
      if (tid >= d) inc += t;
    }
    int ex = inc - s;
    loc[base] = ex; loc[base + 1] = ex + v0;
    loc[base + 2] = ex + v0 + v1; loc[base + 3] = ex + v0 + v1 + v2;
  }
  __syncthreads();

  // phase 3: local reorder into buf (bucket-major); phase 4: reserve global space
#pragma unroll
  for (int j = 0; j < CHUNK / 256; ++j) {
    if (dstv[j] >= 0) {
      int s = ei[e0 + j * 256 + tid];
      int b = dstv[j] >> BSHIFT;
      buf[loc[b] + rankv[j]] = make_uint2((unsigned)s, (unsigned)dstv[j]);
    }
  }
  for (int b = tid; b < nb; b += 256)
    if (hist[b] > 0) gbase[b] = atomicAdd(&bcur[b], hist[b]);
  __syncthreads();

  // phase 5: flush runs (consecutive slots of a bucket -> consecutive global)
  for (int s = tid; s < n; s += 256) {
    uint2 p = buf[s];
    int b = (int)(p.y >> BSHIFT);
    binned[gbase[b] + (s - loc[b])] = p;
  }
}

// Pass B: one block per bucket; scatter bucket's edges + self loops into CSR.
// All ssrc writes land in the bucket's ~35KB window -> L2-resident.
__global__ __launch_bounds__(512) void k_scatter2(
    const uint2* __restrict__ binned, const int* __restrict__ off,
    int* __restrict__ cur, int* __restrict__ ssrc, int Nn) {
  int b = blockIdx.x;
  int tid = threadIdx.x;
  int node0 = b << BSHIFT;
  int nodeEnd = node0 + (1 << BSHIFT); if (nodeEnd > Nn) nodeEnd = Nn;
  int nnodes = nodeEnd - node0;
  // self loops
  if (tid < nnodes) {
    int node = node0 + tid;
    int pos = atomicAdd(&cur[node], 1);
    ssrc[pos] = node;
  }
  int start = off[node0];
  int cnt = off[nodeEnd] - start - nnodes;   // edges in this bucket
  for (int i = tid; i < cnt; i += 512) {
    uint2 p = binned[start + i];
    int pos = atomicAdd(&cur[p.y], 1);
    ssrc[pos] = (int)p.x;
  }
}

// h = x @ W  (64 rows x 128 cols per block, K=128 in chunks of 16)
// epilogue: a_src/a_dst via per-thread 4-col dot + shfl-reduce over 8 lanes/head;
// h stored as packed bf16 pairs (uint per pair), layout [N][64] uints.
__global__ __launch_bounds__(256) void k_gemm_att(
    const float* __restrict__ x, const float* __restrict__ W,
    const float* __restrict__ attS, const float* __restrict__ attD,
    unsigned int* __restrict__ hb, float* __restrict__ aS, float* __restrict__ aD, int Nn) {
  __shared__ float xs[64 * 16];
  __shared__ float ws[16 * 128];
  int tid = threadIdx.x;
  int tx = tid & 31, ty = tid >> 5;
  int node0 = blockIdx.x * 64;
  int col0 = tx * 4;
  float acc[8][4] = {};
  float4 atS = ((const float4*)attS)[tx];
  float4 atD = ((const float4*)attD)[tx];

  for (int k0 = 0; k0 < 128; k0 += 16) {
    {
      int row = tid >> 2;
      int kk = (tid & 3) * 4;
      int gr = node0 + row; if (gr >= Nn) gr = Nn - 1;
      *(float4*)(xs + row * 16 + kk) = *(const float4*)(x + gr * 128 + k0 + kk);
    }
#pragma unroll
    for (int i = 0; i < 2; ++i) {
      int f4 = tid + i * 256;
      int kw = f4 >> 5;
      int cw = (f4 & 31) * 4;
      *(float4*)(ws + kw * 128 + cw) = *(const float4*)(W + (size_t)(k0 + kw) * 128 + cw);
    }
    __syncthreads();
#pragma unroll
    for (int k = 0; k < 16; ++k) {
      float4 b = *(const float4*)(ws + k * 128 + col0);
#pragma unroll
      for (int rr = 0; rr < 8; ++rr) {
        float a = xs[(ty * 8 + rr) * 16 + k];
        acc[rr][0] += a * b.x; acc[rr][1] += a * b.y;
        acc[rr][2] += a * b.z; acc[rr][3] += a * b.w;
      }
    }
    __syncthreads();
  }

  int hgrp = tx >> 3;  // head owned by this 8-lane group
#pragma unroll
  for (int rr = 0; rr < 8; ++rr) {
    int row = node0 + ty * 8 + rr;
    float pS = acc[rr][0] * atS.x + acc[rr][1] * atS.y + acc[rr][2] * atS.z + acc[rr][3] * atS.w;
    float pD = acc[rr][0] * atD.x + acc[rr][1] * atD.y + acc[rr][2] * atD.z + acc[rr][3] * atD.w;
    pS += __shfl_down(pS, 4, 8); pS += __shfl_down(pS, 2, 8); pS += __shfl_down(pS, 1, 8);
    pD += __shfl_down(pD, 4, 8); pD += __shfl_down(pD, 2, 8); pD += __shfl_down(pD, 1, 8);
    if (row < Nn) {
      uint2 pk;
      pk.x = f2bf_pack(acc[rr][0], acc[rr][1]);
      pk.y = f2bf_pack(acc[rr][2], acc[rr][3]);
      *(uint2*)(hb + (size_t)row * 64 + tx * 2) = pk;
      if ((tx & 7) == 0) {
        aS[row * 4 + hgrp] = pS;
        aD[row * 4 + hgrp] = pD;
      }
    }
  }
}

// one wave per dst node; lane l owns output floats [2l, 2l+1] (head = l/16).
// Degree loop unrolled x4 with next-chunk index prefetch.
__global__ __launch_bounds__(256) void k_aggregate(
    const unsigned int* __restrict__ hb, const float* __restrict__ aS, const float* __restrict__ aD,
    const int* __restrict__ off, const int* __restrict__ ssrc,
    const float* __restrict__ bias, float* __restrict__ out, int Nn) {
  int wave = threadIdx.x >> 6;
  int lane = threadIdx.x & 63;
  int node = blockIdx.x * 4 + wave;
  if (node >= Nn) return;
  int hd = lane >> 4;
  float ad = aD[node * 4 + hd];
  int p0 = off[node], p1 = off[node + 1];
  float accx = 0.f, accy = 0.f, den = 0.f;
  int deg = p1 - p0;
  int nch = deg >> 2;
  const int* sp = ssrc + p0;
  int s0 = 0, s1 = 0, s2 = 0, s3 = 0;
  if (nch > 0) { s0 = sp[0]; s1 = sp[1]; s2 = sp[2]; s3 = sp[3]; }
  for (int c = 0; c < nch; ++c) {
    unsigned int v0 = hb[(size_t)s0 * 64 + lane];
    unsigned int v1 = hb[(size_t)s1 * 64 + lane];
    unsigned int v2 = hb[(size_t)s2 * 64 + lane];
    unsigned int v3 = hb[(size_t)s3 * 64 + lane];
    float e0 = aS[s0 * 4 + hd] + ad;
    float e1 = aS[s1 * 4 + hd] + ad;
    float e2 = aS[s2 * 4 + hd] + ad;
    float e3 = aS[s3 * 4 + hd] + ad;
    int t0 = 0, t1 = 0, t2 = 0, t3 = 0;
    if (c + 1 < nch) {
      const int* np = sp + 4;
      t0 = np[0]; t1 = np[1]; t2 = np[2]; t3 = np[3];
    }
    e0 = e0 > 0.f ? e0 : NEG_SLOPE * e0;
    e1 = e1 > 0.f ? e1 : NEG_SLOPE * e1;
    e2 = e2 > 0.f ? e2 : NEG_SLOPE * e2;
    e3 = e3 > 0.f ? e3 : NEG_SLOPE * e3;
    float ex0 = __expf(e0), ex1 = __expf(e1), ex2 = __expf(e2), ex3 = __expf(e3);
    den += ((ex0 + ex1) + (ex2 + ex3));
    accx += ex0 * __uint_as_float(v0 << 16);
    accy += ex0 * __uint_as_float(v0 & 0xffff0000u);
    accx += ex1 * __uint_as_float(v1 << 16);
    accy += ex1 * __uint_as_float(v1 & 0xffff0000u);
    accx += ex2 * __uint_as_float(v2 << 16);
    accy += ex2 * __uint_as_float(v2 & 0xffff0000u);
    accx += ex3 * __uint_as_float(v3 << 16);
    accy += ex3 * __uint_as_float(v3 & 0xffff0000u);
    s0 = t0; s1 = t1; s2 = t2; s3 = t3;
    sp += 4;
  }
  for (int p = p0 + (nch << 2); p < p1; ++p) {
    int src = ssrc[p];
    float e = aS[src * 4 + hd] + ad;
    e = e > 0.f ? e : NEG_SLOPE * e;
    float ex = __expf(e);
    unsigned int v = hb[(size_t)src * 64 + lane];
    accx += ex * __uint_as_float(v << 16);
    accy += ex * __uint_as_float(v & 0xffff0000u);
    den += ex;
  }
  float inv = 1.0f / (den + 1e-16f);
  float2 bv = ((const float2*)bias)[lane];
  float2 o;
  o.x = accx * inv + bv.x;
  o.y = accy * inv + bv.y;
  ((float2*)out)[(size_t)node * 64 + lane] = o;
}

extern "C" void kernel_launch(void* const* d_in, const int* in_sizes, int n_in,
                              void* d_out, int out_size, void* d_ws, size_t ws_size,
                              hipStream_t stream) {
  const float* x    = (const float*)d_in[0];
  const int*   ei   = (const int*)d_in[1];
  const float* W    = (const float*)d_in[2];
  const float* attS = (const float*)d_in[3];
  const float* attD = (const float*)d_in[4];
  const float* bias = (const float*)d_in[5];
  float* out = (float*)d_out;

  const int Nn = in_sizes[0] / 128;
  const int E  = in_sizes[1] / 2;
  const int B1 = (Nn + 2047) / 2048;
  const int nb = (Nn + (1 << BSHIFT) - 1) >> BSHIFT;

  // workspace layout (256B aligned)
  char* ws = (char*)d_ws;
  size_t o = 0;
  auto take = [&](size_t bytes) { void* p = ws + o; o += (bytes + 255) & ~(size_t)255; return p; };
  int*   off     = (int*)take((size_t)(Nn + 1) * 4);
  int*   cur     = (int*)take((size_t)Nn * 4);
  int*   ssrc    = (int*)take((size_t)(E + Nn) * 4);
  int*   partial = (int*)take((size_t)(B1 + 1) * 4);
  int*   bcur    = (int*)take((size_t)NB_MAX * 4);
  float* aS      = (float*)take((size_t)Nn * 4 * 4);
  float* aD      = (float*)take((size_t)Nn * 4 * 4);
  unsigned int* hb = (unsigned int*)take((size_t)Nn * 64 * 4);  // bf16-packed h
  uint2* binned  = (uint2*)hb;   // aliased: binned dies before k_gemm_att writes hb
  (void)ws_size; (void)o;

  k_init_deg<<<(Nn + 255) / 256, 256, 0, stream>>>(cur, Nn);
  k_hist<<<(E + 255) / 256, 256, 0, stream>>>(ei, cur, E);
  k_scan1<<<B1, 256, 0, stream>>>(cur, partial, Nn);
  k_scan2<<<1, 64, 0, stream>>>(partial, off, B1, E + Nn, Nn);
  k_scan3<<<B1, 256, 0, stream>>>(cur, off, partial, Nn);
  k_bcur_init<<<(nb + 255) / 256, 256, 0, stream>>>(off, bcur, nb);
  k_bin<<<(E + CHUNK - 1) / CHUNK, 256, 0, stream>>>(ei, bcur, binned, E, nb);
  k_scatter2<<<nb, 512, 0, stream>>>(binned, off, cur, ssrc, Nn);
  k_gemm_att<<<(Nn + 63) / 64, 256, 0, stream>>>(x, W, attS, attD, hb, aS, aD, Nn);
  k_aggregate<<<(Nn + 3) / 4, 256, 0, stream>>>(hb, aS, aD, off, ssrc, bias, out, Nn);
}

// Round 4
// 278.975 us; speedup vs baseline: 1.9328x; 1.3431x over previous
//
#include <hip/hip_runtime.h>

// GAT conv forward: N=100000 nodes, E=1.6M edges (+N self loops), IN_F=128,
// OUT_F=32, HEADS=4. Pipeline (R4):
//   1. k_wprep: W -> W^T bf16 (32KB, L2-resident B operand)
//   2. k_bucket_hist + k_bucket_scan: 256-bucket (dst>>9) edge histogram + scan
//      (replaces R3's 1.6M-global-atomic per-node hist + 3-kernel scan)
//   3. k_bin: bin edges by bucket into packed uints (src | dstLocal<<20)
//   4. k_scatter2: per bucket, LDS degree-count + scan + counting sort ->
//      off[] and coalesced ssrc writes (self loop first in each segment)
//   5. k_gemm: h = x@W via mfma_f32_16x16x32_bf16, no LDS; hb stored as
//      bf16 pairs (col c, c+16 of same head) so packing is lane-local
//   6. k_att: aS/aD = <h, att> per head (coalesced, shfl-reduce)
//   7. k_aggregate: one wave per dst node; unnormalized softmax, register
//      accumulation, x4 unroll + index prefetch (R3: 84us, VALU 76%)

#define NEG_SLOPE 0.2f
#define NB_MAX 256      // buckets (Nn <= 131072)
#define BSHIFT 9        // 512 nodes per bucket
#define CHUNK 4096      // edges per binning block
#define CAP 11264       // max edges+selfloops per bucket (mean ~8700, 30+ sigma)

typedef __attribute__((ext_vector_type(8))) short short8;
typedef __attribute__((ext_vector_type(4))) float f32x4;

__device__ __forceinline__ unsigned int rne16(unsigned int u) {
  return (u + 0x7fffu + ((u >> 16) & 1u)) >> 16;
}
__device__ __forceinline__ unsigned int f2bf_pack(float a, float b) {
  return (rne16(__float_as_uint(b)) << 16) | (rne16(__float_as_uint(a)) & 0xffffu);
}

// W[k][col] fp32 -> Wt[col][k] bf16 (RNE)
__global__ void k_wprep(const float* __restrict__ W, unsigned short* __restrict__ Wt) {
  int idx = blockIdx.x * 256 + threadIdx.x;   // 16384 total
  int k = idx >> 7, col = idx & 127;
  Wt[col * 128 + k] = (unsigned short)rne16(__float_as_uint(W[idx]));
}

__global__ __launch_bounds__(256) void k_bucket_hist(
    const int* __restrict__ ei, int* __restrict__ bucketCnt, int E) {
  __shared__ int h[NB_MAX];
  int tid = threadIdx.x;
  h[tid] = 0;
  __syncthreads();
  int base = blockIdx.x * CHUNK;
  int n = E - base; if (n > CHUNK) n = CHUNK;
  for (int i = tid; i < n; i += 256) atomicAdd(&h[ei[E + base + i] >> BSHIFT], 1);
  __syncthreads();
  if (h[tid]) atomicAdd(&bucketCnt[tid], h[tid]);
}

// single wave: exclusive scan of 256 bucket counts -> bucketOff, bcur
__global__ void k_bucket_scan(const int* __restrict__ bucketCnt,
                              int* __restrict__ bucketOff, int* __restrict__ bcur) {
  int lane = threadIdx.x;  // 64
  int base = lane * 4;
  int v0 = bucketCnt[base], v1 = bucketCnt[base + 1];
  int v2 = bucketCnt[base + 2], v3 = bucketCnt[base + 3];
  int s = v0 + v1 + v2 + v3;
  int inc = s;
#pragma unroll
  for (int d = 1; d < 64; d <<= 1) {
    int t = __shfl_up(inc, d, 64);
    if (lane >= d) inc += t;
  }
  int ex = inc - s;
  bucketOff[base] = ex;          bcur[base] = ex;
  bucketOff[base + 1] = ex + v0; bcur[base + 1] = ex + v0;
  bucketOff[base + 2] = ex + v0 + v1; bcur[base + 2] = ex + v0 + v1;
  bucketOff[base + 3] = ex + v0 + v1 + v2; bcur[base + 3] = ex + v0 + v1 + v2;
  if (lane == 63) bucketOff[256] = inc;   // total E
}

// bin (src,dst) by dst>>9 into per-bucket regions, packed src|dstLocal<<20
__global__ __launch_bounds__(256) void k_bin(
    const int* __restrict__ ei, int* __restrict__ bcur,
    unsigned int* __restrict__ binned, int E, int nb) {
  __shared__ uint2 buf[CHUNK];          // 32 KB reordered pairs
  __shared__ int hist[NB_MAX];
  __shared__ int loc[NB_MAX];
  __shared__ int gbase[NB_MAX];
  int tid = threadIdx.x;
  int e0 = blockIdx.x * CHUNK;
  int n = E - e0; if (n > CHUNK) n = CHUNK;

  for (int i = tid; i < NB_MAX; i += 256) hist[i] = 0;
  __syncthreads();

  int dstv[CHUNK / 256];
  int rankv[CHUNK / 256];
#pragma unroll
  for (int j = 0; j < CHUNK / 256; ++j) {
    int idx = j * 256 + tid;
    dstv[j] = -1;
    if (idx < n) {
      int d = ei[E + e0 + idx];
      dstv[j] = d;
      rankv[j] = atomicAdd(&hist[d >> BSHIFT], 1);
    }
  }
  __syncthreads();

  if (tid < 64) {
    int base = tid * 4;
    int v0 = hist[base], v1 = hist[base + 1], v2 = hist[base + 2], v3 = hist[base + 3];
    int s = v0 + v1 + v2 + v3;
    int inc = s;
#pragma unroll
    for (int d = 1; d < 64; d <<= 1) {
      int t = __shfl_up(inc, d, 64);
      if (tid >= d) inc += t;
    }
    int ex = inc - s;
    loc[base] = ex; loc[base + 1] = ex + v0;
    loc[base + 2] = ex + v0 + v1; loc[base + 3] = ex + v0 + v1 + v2;
  }
  __syncthreads();

#pragma unroll
  for (int j = 0; j < CHUNK / 256; ++j) {
    if (dstv[j] >= 0) {
      int s = ei[e0 + j * 256 + tid];
      int b = dstv[j] >> BSHIFT;
      buf[loc[b] + rankv[j]] = make_uint2((unsigned)s, (unsigned)dstv[j]);
    }
  }
  for (int b = tid; b < nb; b += 256)
    if (hist[b] > 0) gbase[b] = atomicAdd(&bcur[b], hist[b]);
  __syncthreads();

  for (int s = tid; s < n; s += 256) {
    uint2 p = buf[s];
    int b = (int)(p.y >> BSHIFT);
    binned[gbase[b] + (s - loc[b])] = p.x | ((p.y & 511u) << 20);
  }
}

// per bucket: LDS degree count + scan -> off[], counting-sort -> coalesced ssrc
__global__ __launch_bounds__(256) void k_scatter2(
    const unsigned int* __restrict__ binned, const int* __restrict__ bucketOff,
    int* __restrict__ off, int* __restrict__ ssrc, int Nn, int E, int nb) {
  __shared__ int cnt[512];
  __shared__ int loc[512];
  __shared__ int obuf[CAP];
  __shared__ int wsum[4];
  int b = blockIdx.x, tid = threadIdx.x;
  int node0 = b << BSHIFT;
  int nnodes = Nn - node0; if (nnodes > 512) nnodes = 512;
  int base = bucketOff[b];
  int nE = bucketOff[b + 1] - base;

  cnt[tid] = 0; cnt[tid + 256] = 0;
  __syncthreads();
  for (int i = tid; i < nE; i += 256)
    atomicAdd(&cnt[(binned[base + i] >> 20) & 511u], 1);
  __syncthreads();

  // exclusive scan of (cnt[i] + selfloop) over 512, 2 per thread
  int i0 = 2 * tid, i1 = 2 * tid + 1;
  int v0 = cnt[i0] + (i0 < nnodes ? 1 : 0);
  int v1 = cnt[i1] + (i1 < nnodes ? 1 : 0);
  int s = v0 + v1;
  int lane = tid & 63, w = tid >> 6;
  int inc = s;
#pragma unroll
  for (int d = 1; d < 64; d <<= 1) {
    int t = __shfl_up(inc, d, 64);
    if (lane >= d) inc += t;
  }
  if (lane == 63) wsum[w] = inc;
  __syncthreads();
  int wbase = 0;
  for (int ww = 0; ww < w; ++ww) wbase += wsum[ww];
  int ex = wbase + inc - s;
  loc[i0] = ex; loc[i1] = ex + v0;
  __syncthreads();

  int csrBase = base + node0;  // edges before + self loops before
  // write off[] + self loop at segment head; reset cnt as cursor
  for (int i = tid; i < nnodes; i += 256) {
    int l = loc[i];
    off[node0 + i] = csrBase + l;
    obuf[l] = node0 + i;
  }
  for (int i = tid; i < 512; i += 256) cnt[i] = loc[i] + 1;
  __syncthreads();

  for (int i = tid; i < nE; i += 256) {
    unsigned p = binned[base + i];
    int d = (p >> 20) & 511u;
    int pos = atomicAdd(&cnt[d], 1);
    if (pos < CAP) obuf[pos] = (int)(p & 0xFFFFFu);
  }
  __syncthreads();

  int tot = nE + nnodes;
  for (int i = tid; i < tot; i += 256) ssrc[csrBase + i] = obuf[i];
  if (b == nb - 1 && tid == 0) off[Nn] = E + Nn;
}

// h = x@W via MFMA bf16. Block = 4 waves x 16 rows. Per wave: 8 n-tiles,
// A from global fp32 (lane m=lane&15 reads 8 consecutive k), B from Wt bf16.
// hb[row][u*16+c] packs (col 32u+c, col 32u+c+16) -- lane-local from C layout.
__global__ __launch_bounds__(256) void k_gemm(
    const float* __restrict__ x, const unsigned short* __restrict__ Wt,
    unsigned int* __restrict__ hb, int Nn) {
  int tid = threadIdx.x;
  int w = tid >> 6, lane = tid & 63;
  int m = lane & 15, q = lane >> 4;
  int r0 = blockIdx.x * 64 + w * 16;
  int rowA = r0 + m; if (rowA >= Nn) rowA = Nn - 1;
  const float* xrow = x + (size_t)rowA * 128;

  f32x4 acc[8];
#pragma unroll
  for (int t = 0; t < 8; ++t) acc[t] = (f32x4){0.f, 0.f, 0.f, 0.f};

#pragma unroll
  for (int ks = 0; ks < 4; ++ks) {
    int k0 = ks * 32 + q * 8;
    float4 a0 = *(const float4*)(xrow + k0);
    float4 a1 = *(const float4*)(xrow + k0 + 4);
    unsigned au[4];
    au[0] = f2bf_pack(a0.x, a0.y);
    au[1] = f2bf_pack(a0.z, a0.w);
    au[2] = f2bf_pack(a1.x, a1.y);
    au[3] = f2bf_pack(a1.z, a1.w);
    short8 af = *(short8*)au;
#pragma unroll
    for (int t = 0; t < 8; ++t) {
      short8 bf = *(const short8*)(Wt + (t * 16 + m) * 128 + k0);
      acc[t] = __builtin_amdgcn_mfma_f32_16x16x32_bf16(af, bf, acc[t], 0, 0, 0);
    }
  }

  // C layout: col = lane&15 (=m), row = q*4 + reg
#pragma unroll
  for (int r = 0; r < 4; ++r) {
    int rowo = r0 + q * 4 + r;
    if (rowo < Nn) {
#pragma unroll
      for (int u = 0; u < 4; ++u) {
        hb[(size_t)rowo * 64 + u * 16 + m] = f2bf_pack(acc[2 * u][r], acc[2 * u + 1][r]);
      }
    }
  }
}

// aS/aD from hb: wave per node, shfl-reduce over 16 lanes per head
__global__ __launch_bounds__(256) void k_att(
    const unsigned int* __restrict__ hb, const float* __restrict__ attS,
    const float* __restrict__ attD, float* __restrict__ aS, float* __restrict__ aD, int Nn) {
  int wv = threadIdx.x >> 6, lane = threadIdx.x & 63;
  int node = blockIdx.x * 4 + wv;
  if (node >= Nn) return;
  int u = lane >> 4, c = lane & 15;
  unsigned v = hb[(size_t)node * 64 + lane];
  float fx = __uint_as_float(v << 16);
  float fy = __uint_as_float(v & 0xffff0000u);
  float pS = fx * attS[u * 32 + c] + fy * attS[u * 32 + c + 16];
  float pD = fx * attD[u * 32 + c] + fy * attD[u * 32 + c + 16];
#pragma unroll
  for (int d = 8; d >= 1; d >>= 1) {
    pS += __shfl_down(pS, d, 16);
    pD += __shfl_down(pD, d, 16);
  }
  if (c == 0) { aS[node * 4 + u] = pS; aD[node * 4 + u] = pD; }
}

// one wave per dst node; lane l = u*16+c owns cols (32u+c, 32u+c+16), head u.
__global__ __launch_bounds__(256) void k_aggregate(
    const unsigned int* __restrict__ hb, const float* __restrict__ aS, const float* __restrict__ aD,
    const int* __restrict__ off, const int* __restrict__ ssrc,
    const float* __restrict__ bias, float* __restrict__ out, int Nn) {
  int wave = threadIdx.x >> 6;
  int lane = threadIdx.x & 63;
  int node = blockIdx.x * 4 + wave;
  if (node >= Nn) return;
  int hd = lane >> 4;
  float ad = aD[node * 4 + hd];
  int p0 = off[node], p1 = off[node + 1];
  float accx = 0.f, accy = 0.f, den = 0.f;
  int deg = p1 - p0;
  int nch = deg >> 2;
  const int* sp = ssrc + p0;
  int s0 = 0, s1 = 0, s2 = 0, s3 = 0;
  if (nch > 0) { s0 = sp[0]; s1 = sp[1]; s2 = sp[2]; s3 = sp[3]; }
  for (int c = 0; c < nch; ++c) {
    unsigned int v0 = hb[(size_t)s0 * 64 + lane];
    unsigned int v1 = hb[(size_t)s1 * 64 + lane];
    unsigned int v2 = hb[(size_t)s2 * 64 + lane];
    unsigned int v3 = hb[(size_t)s3 * 64 + lane];
    float e0 = aS[s0 * 4 + hd] + ad;
    float e1 = aS[s1 * 4 + hd] + ad;
    float e2 = aS[s2 * 4 + hd] + ad;
    float e3 = aS[s3 * 4 + hd] + ad;
    int t0 = 0, t1 = 0, t2 = 0, t3 = 0;
    if (c + 1 < nch) {
      const int* np = sp + 4;
      t0 = np[0]; t1 = np[1]; t2 = np[2]; t3 = np[3];
    }
    e0 = e0 > 0.f ? e0 : NEG_SLOPE * e0;
    e1 = e1 > 0.f ? e1 : NEG_SLOPE * e1;
    e2 = e2 > 0.f ? e2 : NEG_SLOPE * e2;
    e3 = e3 > 0.f ? e3 : NEG_SLOPE * e3;
    float ex0 = __expf(e0), ex1 = __expf(e1), ex2 = __expf(e2), ex3 = __expf(e3);
    den += ((ex0 + ex1) + (ex2 + ex3));
    accx += ex0 * __uint_as_float(v0 << 16);
    accy += ex0 * __uint_as_float(v0 & 0xffff0000u);
    accx += ex1 * __uint_as_float(v1 << 16);
    accy += ex1 * __uint_as_float(v1 & 0xffff0000u);
    accx += ex2 * __uint_as_float(v2 << 16);
    accy += ex2 * __uint_as_float(v2 & 0xffff0000u);
    accx += ex3 * __uint_as_float(v3 << 16);
    accy += ex3 * __uint_as_float(v3 & 0xffff0000u);
    s0 = t0; s1 = t1; s2 = t2; s3 = t3;
    sp += 4;
  }
  for (int p = p0 + (nch << 2); p < p1; ++p) {
    int src = ssrc[p];
    float e = aS[src * 4 + hd] + ad;
    e = e > 0.f ? e : NEG_SLOPE * e;
    float ex = __expf(e);
    unsigned int v = hb[(size_t)src * 64 + lane];
    accx += ex * __uint_as_float(v << 16);
    accy += ex * __uint_as_float(v & 0xffff0000u);
    den += ex;
  }
  float inv = 1.0f / (den + 1e-16f);
  int col = hd * 32 + (lane & 15);
  out[(size_t)node * 128 + col] = accx * inv + bias[col];
  out[(size_t)node * 128 + col + 16] = accy * inv + bias[col + 16];
}

extern "C" void kernel_launch(void* const* d_in, const int* in_sizes, int n_in,
                              void* d_out, int out_size, void* d_ws, size_t ws_size,
                              hipStream_t stream) {
  const float* x    = (const float*)d_in[0];
  const int*   ei   = (const int*)d_in[1];
  const float* W    = (const float*)d_in[2];
  const float* attS = (const float*)d_in[3];
  const float* attD = (const float*)d_in[4];
  const float* bias = (const float*)d_in[5];
  float* out = (float*)d_out;

  const int Nn = in_sizes[0] / 128;
  const int E  = in_sizes[1] / 2;
  const int nb = (Nn + (1 << BSHIFT) - 1) >> BSHIFT;

  char* ws = (char*)d_ws;
  size_t o = 0;
  auto take = [&](size_t bytes) { void* p = ws + o; o += (bytes + 255) & ~(size_t)255; return p; };
  int* off       = (int*)take((size_t)(Nn + 1) * 4);
  int* ssrc      = (int*)take((size_t)(E + Nn) * 4);
  int* bucketCnt = (int*)take((size_t)NB_MAX * 4);
  int* bucketOff = (int*)take((size_t)(NB_MAX + 1) * 4);
  int* bcur      = (int*)take((size_t)NB_MAX * 4);
  float* aS      = (float*)take((size_t)Nn * 4 * 4);
  float* aD      = (float*)take((size_t)Nn * 4 * 4);
  unsigned short* Wt = (unsigned short*)take((size_t)128 * 128 * 2);
  unsigned int* hb = (unsigned int*)take((size_t)Nn * 64 * 4);
  unsigned int* binned = (unsigned int*)hb;  // alias: binned dies before k_gemm writes hb
  (void)ws_size; (void)o;

  hipMemsetAsync(bucketCnt, 0, NB_MAX * 4, stream);
  k_wprep<<<64, 256, 0, stream>>>(W, Wt);
  k_bucket_hist<<<(E + CHUNK - 1) / CHUNK, 256, 0, stream>>>(ei, bucketCnt, E);
  k_bucket_scan<<<1, 64, 0, stream>>>(bucketCnt, bucketOff, bcur);
  k_bin<<<(E + CHUNK - 1) / CHUNK, 256, 0, stream>>>(ei, bcur, binned, E, nb);
  k_scatter2<<<nb, 256, 0, stream>>>(binned, bucketOff, off, ssrc, Nn, E, nb);
  k_gemm<<<(Nn + 63) / 64, 256, 0, stream>>>(x, Wt, hb, Nn);
  k_att<<<(Nn + 3) / 4, 256, 0, stream>>>(hb, attS, attD, aS, aD, Nn);
  k_aggregate<<<(Nn + 3) / 4, 256, 0, stream>>>(hb, aS, aD, off, ssrc, bias, out, Nn);
}

// Round 5
// 252.422 us; speedup vs baseline: 2.1361x; 1.1052x over previous
//
#include <hip/hip_runtime.h>

// GAT conv forward: N=100000 nodes, E=1.6M edges (+N self loops), IN_F=128,
// OUT_F=32, HEADS=4. Pipeline (R5, 6 dispatches):
//   1. memset bucketCnt
//   2. k_hist_prep: 256-bucket (dst>>9) edge histogram  +  W->W^T bf16 prep
//   3. k_bucket_scan: 1-wave exclusive scan -> bucketOff/bcur
//   4. k_binmm (fat): blocks [0,nbBin) bin edges by bucket (packed
//      src|dstLocal<<20); blocks [nbBin,..) do h=x@W via mfma bf16 with
//      fused a_src/a_dst epilogue (acc-register dot + width-16 shfl reduce).
//      Independent chains overlap in one dispatch. binned is NOT aliased
//      with hb (concurrent writers).
//   5. k_scatter2: per bucket LDS counting-sort -> off[] + coalesced ssrc
//   6. k_aggregate: one wave per dst; SCALARIZED addressing (R4 showed
//      VALUBusy 84% from 64-bit vector address math): readfirstlane ->
//      s_load indices, SGPR-base gathers. Unnormalized softmax, zero atomics.

#define NEG_SLOPE 0.2f
#define NB_MAX 256      // buckets (Nn <= 131072)
#define BSHIFT 9        // 512 nodes per bucket
#define CHUNK 4096      // edges per binning block
#define CAP 11264       // max edges+selfloops per bucket (mean ~8700, 30+ sigma)

typedef __attribute__((ext_vector_type(8))) short short8;
typedef __attribute__((ext_vector_type(4))) float f32x4;

__device__ __forceinline__ unsigned int rne16(unsigned int u) {
  return (u + 0x7fffu + ((u >> 16) & 1u)) >> 16;
}
__device__ __forceinline__ unsigned int f2bf_pack(float a, float b) {
  return (rne16(__float_as_uint(b)) << 16) | (rne16(__float_as_uint(a)) & 0xffffu);
}

// blocks [0,nbBin): bucket histogram; blocks [nbBin,nbBin+64): W^T bf16 prep
__global__ __launch_bounds__(256) void k_hist_prep(
    const int* __restrict__ ei, int* __restrict__ bucketCnt, int E,
    const float* __restrict__ W, unsigned short* __restrict__ Wt, int nbBin) {
  __shared__ int h[NB_MAX];
  int tid = threadIdx.x;
  if ((int)blockIdx.x >= nbBin) {
    int idx = (blockIdx.x - nbBin) * 256 + tid;   // 16384 total
    int k = idx >> 7, col = idx & 127;
    Wt[col * 128 + k] = (unsigned short)rne16(__float_as_uint(W[idx]));
    return;
  }
  h[tid] = 0;
  __syncthreads();
  int base = blockIdx.x * CHUNK;
  int n = E - base; if (n > CHUNK) n = CHUNK;
  for (int i = tid; i < n; i += 256) atomicAdd(&h[ei[E + base + i] >> BSHIFT], 1);
  __syncthreads();
  if (h[tid]) atomicAdd(&bucketCnt[tid], h[tid]);
}

// single wave: exclusive scan of 256 bucket counts -> bucketOff, bcur
__global__ void k_bucket_scan(const int* __restrict__ bucketCnt,
                              int* __restrict__ bucketOff, int* __restrict__ bcur) {
  int lane = threadIdx.x;  // 64
  int base = lane * 4;
  int v0 = bucketCnt[base], v1 = bucketCnt[base + 1];
  int v2 = bucketCnt[base + 2], v3 = bucketCnt[base + 3];
  int s = v0 + v1 + v2 + v3;
  int inc = s;
#pragma unroll
  for (int d = 1; d < 64; d <<= 1) {
    int t = __shfl_up(inc, d, 64);
    if (lane >= d) inc += t;
  }
  int ex = inc - s;
  bucketOff[base] = ex;          bcur[base] = ex;
  bucketOff[base + 1] = ex + v0; bcur[base + 1] = ex + v0;
  bucketOff[base + 2] = ex + v0 + v1; bcur[base + 2] = ex + v0 + v1;
  bucketOff[base + 3] = ex + v0 + v1 + v2; bcur[base + 3] = ex + v0 + v1 + v2;
  if (lane == 63) bucketOff[256] = inc;   // total E
}

// FAT kernel: bin path + gemm(+att) path in one dispatch for overlap.
__global__ __launch_bounds__(256) void k_binmm(
    const int* __restrict__ ei, int* __restrict__ bcur,
    unsigned int* __restrict__ binned, int E, int nb, int nbBin,
    const float* __restrict__ x, const unsigned short* __restrict__ Wt,
    unsigned int* __restrict__ hb,
    const float* __restrict__ attS, const float* __restrict__ attD,
    float* __restrict__ aS, float* __restrict__ aD, int Nn) {
  __shared__ uint2 buf[CHUNK];          // 32 KB (bin path only)
  __shared__ int hist[NB_MAX];
  __shared__ int loc[NB_MAX];
  __shared__ int gbase[NB_MAX];
  int tid = threadIdx.x;

  if ((int)blockIdx.x < nbBin) {
    // ---------------- bin path ----------------
    int e0 = blockIdx.x * CHUNK;
    int n = E - e0; if (n > CHUNK) n = CHUNK;

    for (int i = tid; i < NB_MAX; i += 256) hist[i] = 0;
    __syncthreads();

    int dstv[CHUNK / 256];
    int rankv[CHUNK / 256];
#pragma unroll
    for (int j = 0; j < CHUNK / 256; ++j) {
      int idx = j * 256 + tid;
      dstv[j] = -1;
      if (idx < n) {
        int d = ei[E + e0 + idx];
        dstv[j] = d;
        rankv[j] = atomicAdd(&hist[d >> BSHIFT], 1);
      }
    }
    __syncthreads();

    if (tid < 64) {
      int base = tid * 4;
      int v0 = hist[base], v1 = hist[base + 1], v2 = hist[base + 2], v3 = hist[base + 3];
      int s = v0 + v1 + v2 + v3;
      int inc = s;
#pragma unroll
      for (int d = 1; d < 64; d <<= 1) {
        int t = __shfl_up(inc, d, 64);
        if (tid >= d) inc += t;
      }
      int ex = inc - s;
      loc[base] = ex; loc[base + 1] = ex + v0;
      loc[base + 2] = ex + v0 + v1; loc[base + 3] = ex + v0 + v1 + v2;
    }
    __syncthreads();

#pragma unroll
    for (int j = 0; j < CHUNK / 256; ++j) {
      if (dstv[j] >= 0) {
        int s = ei[e0 + j * 256 + tid];
        int b = dstv[j] >> BSHIFT;
        buf[loc[b] + rankv[j]] = make_uint2((unsigned)s, (unsigned)dstv[j]);
      }
    }
    for (int b = tid; b < nb; b += 256)
      if (hist[b] > 0) gbase[b] = atomicAdd(&bcur[b], hist[b]);
    __syncthreads();

    for (int s = tid; s < n; s += 256) {
      uint2 p = buf[s];
      int b = (int)(p.y >> BSHIFT);
      binned[gbase[b] + (s - loc[b])] = p.x | ((p.y & 511u) << 20);
    }
    return;
  }

  // ---------------- gemm + att path ----------------
  int gbid = blockIdx.x - nbBin;
  int w = tid >> 6, lane = tid & 63;
  int m = lane & 15, q = lane >> 4;
  int r0 = gbid * 64 + w * 16;
  int rowA = r0 + m; if (rowA >= Nn) rowA = Nn - 1;
  const float* xrow = x + (unsigned)rowA * 128u;

  f32x4 acc[8];
#pragma unroll
  for (int t = 0; t < 8; ++t) acc[t] = (f32x4){0.f, 0.f, 0.f, 0.f};

#pragma unroll
  for (int ks = 0; ks < 4; ++ks) {
    int k0 = ks * 32 + q * 8;
    float4 a0 = *(const float4*)(xrow + k0);
    float4 a1 = *(const float4*)(xrow + k0 + 4);
    unsigned au[4];
    au[0] = f2bf_pack(a0.x, a0.y);
    au[1] = f2bf_pack(a0.z, a0.w);
    au[2] = f2bf_pack(a1.x, a1.y);
    au[3] = f2bf_pack(a1.z, a1.w);
    short8 af = *(short8*)au;
#pragma unroll
    for (int t = 0; t < 8; ++t) {
      short8 bf = *(const short8*)(Wt + (unsigned)(t * 16 + m) * 128u + k0);
      acc[t] = __builtin_amdgcn_mfma_f32_16x16x32_bf16(af, bf, acc[t], 0, 0, 0);
    }
  }

  // att vector slices owned by this lane: head u cols 32u+m and 32u+m+16
  float sSa[4], sSb[4], sDa[4], sDb[4];
#pragma unroll
  for (int u = 0; u < 4; ++u) {
    sSa[u] = attS[u * 32 + m]; sSb[u] = attS[u * 32 + m + 16];
    sDa[u] = attD[u * 32 + m]; sDb[u] = attD[u * 32 + m + 16];
  }

  // C layout: col = m, row = q*4 + reg
#pragma unroll
  for (int r = 0; r < 4; ++r) {
    int rowo = r0 + q * 4 + r;
    bool ok = rowo < Nn;
    if (ok) {
#pragma unroll
      for (int u = 0; u < 4; ++u)
        hb[(unsigned)rowo * 64u + u * 16 + m] = f2bf_pack(acc[2 * u][r], acc[2 * u + 1][r]);
    }
#pragma unroll
    for (int u = 0; u < 4; ++u) {
      float pS = acc[2 * u][r] * sSa[u] + acc[2 * u + 1][r] * sSb[u];
      float pD = acc[2 * u][r] * sDa[u] + acc[2 * u + 1][r] * sDb[u];
#pragma unroll
      for (int d = 8; d >= 1; d >>= 1) {
        pS += __shfl_down(pS, d, 16);
        pD += __shfl_down(pD, d, 16);
      }
      if (ok && m == 0) {
        aS[(unsigned)rowo * 4u + u] = pS;
        aD[(unsigned)rowo * 4u + u] = pD;
      }
    }
  }
}

// per bucket: LDS degree count + scan -> off[], counting-sort -> coalesced ssrc
__global__ __launch_bounds__(256) void k_scatter2(
    const unsigned int* __restrict__ binned, const int* __restrict__ bucketOff,
    int* __restrict__ off, int* __restrict__ ssrc, int Nn, int E, int nb) {
  __shared__ int cnt[512];
  __shared__ int loc[512];
  __shared__ int obuf[CAP];
  __shared__ int wsum[4];
  int b = blockIdx.x, tid = threadIdx.x;
  int node0 = b << BSHIFT;
  int nnodes = Nn - node0; if (nnodes > 512) nnodes = 512;
  int base = bucketOff[b];
  int nE = bucketOff[b + 1] - base;

  cnt[tid] = 0; cnt[tid + 256] = 0;
  __syncthreads();
  for (int i = tid; i < nE; i += 256)
    atomicAdd(&cnt[(binned[base + i] >> 20) & 511u], 1);
  __syncthreads();

  int i0 = 2 * tid, i1 = 2 * tid + 1;
  int v0 = cnt[i0] + (i0 < nnodes ? 1 : 0);
  int v1 = cnt[i1] + (i1 < nnodes ? 1 : 0);
  int s = v0 + v1;
  int lane = tid & 63, w = tid >> 6;
  int inc = s;
#pragma unroll
  for (int d = 1; d < 64; d <<= 1) {
    int t = __shfl_up(inc, d, 64);
    if (lane >= d) inc += t;
  }
  if (lane == 63) wsum[w] = inc;
  __syncthreads();
  int wbase = 0;
  for (int ww = 0; ww < w; ++ww) wbase += wsum[ww];
  int ex = wbase + inc - s;
  loc[i0] = ex; loc[i1] = ex + v0;
  __syncthreads();

  int csrBase = base + node0;  // edges before + self loops before
  for (int i = tid; i < nnodes; i += 256) {
    int l = loc[i];
    off[node0 + i] = csrBase + l;
    obuf[l] = node0 + i;       // self loop at segment head
  }
  for (int i = tid; i < 512; i += 256) cnt[i] = loc[i] + 1;
  __syncthreads();

  for (int i = tid; i < nE; i += 256) {
    unsigned p = binned[base + i];
    int d = (p >> 20) & 511u;
    int pos = atomicAdd(&cnt[d], 1);
    if (pos < CAP) obuf[pos] = (int)(p & 0xFFFFFu);
  }
  __syncthreads();

  int tot = nE + nnodes;
  for (int i = tid; i < tot; i += 256) ssrc[csrBase + i] = obuf[i];
  if (b == nb - 1 && tid == 0) off[Nn] = E + Nn;
}

// one wave per dst node; lane l = u*16+c owns cols (32u+c, 32u+c+16), head u.
// Scalarized: node/p0/p1/edge-indices in SGPRs -> s_load + SGPR-base gathers.
__global__ __launch_bounds__(256) void k_aggregate(
    const unsigned int* __restrict__ hb, const float* __restrict__ aS, const float* __restrict__ aD,
    const int* __restrict__ off, const int* __restrict__ ssrc,
    const float* __restrict__ bias, float* __restrict__ out, int Nn) {
  int wave = threadIdx.x >> 6;
  int lane = threadIdx.x & 63;
  int node = blockIdx.x * 4 + wave;
  if (node >= Nn) return;
  int un = __builtin_amdgcn_readfirstlane(node);   // SGPR: wave-uniform
  unsigned hd = (unsigned)lane >> 4;
  float ad = aD[(unsigned)un * 4u + hd];
  int p0 = off[un], p1 = off[un + 1];              // uniform -> s_load
  const int* sp = ssrc + p0;                       // uniform pointer
  int deg = p1 - p0;
  int nch = deg >> 2;
  float accx = 0.f, accy = 0.f, den = 0.f;

  for (int c = 0; c < nch; ++c) {
    int s0 = sp[0], s1 = sp[1], s2 = sp[2], s3 = sp[3];  // s_load_dwordx4
    unsigned v0 = hb[(unsigned)s0 * 64u + lane];   // saddr-form gathers
    unsigned v1 = hb[(unsigned)s1 * 64u + lane];
    unsigned v2 = hb[(unsigned)s2 * 64u + lane];
    unsigned v3 = hb[(unsigned)s3 * 64u + lane];
    float e0 = aS[(unsigned)s0 * 4u + hd] + ad;
    float e1 = aS[(unsigned)s1 * 4u + hd] + ad;
    float e2 = aS[(unsigned)s2 * 4u + hd] + ad;
    float e3 = aS[(unsigned)s3 * 4u + hd] + ad;
    e0 = e0 > 0.f ? e0 : NEG_SLOPE * e0;
    e1 = e1 > 0.f ? e1 : NEG_SLOPE * e1;
    e2 = e2 > 0.f ? e2 : NEG_SLOPE * e2;
    e3 = e3 > 0.f ? e3 : NEG_SLOPE * e3;
    float ex0 = __expf(e0), ex1 = __expf(e1), ex2 = __expf(e2), ex3 = __expf(e3);
    den += ((ex0 + ex1) + (ex2 + ex3));
    accx += ex0 * __uint_as_float(v0 << 16);
    accy += ex0 * __uint_as_float(v0 & 0xffff0000u);
    accx += ex1 * __uint_as_float(v1 << 16);
    accy += ex1 * __uint_as_float(v1 & 0xffff0000u);
    accx += ex2 * __uint_as_float(v2 << 16);
    accy += ex2 * __uint_as_float(v2 & 0xffff0000u);
    accx += ex3 * __uint_as_float(v3 << 16);
    accy += ex3 * __uint_as_float(v3 & 0xffff0000u);
    sp += 4;
  }
  for (int p = nch << 2; p < deg; ++p) {
    int src = (ssrc + p0)[p];                      // uniform -> s_load
    float e = aS[(unsigned)src * 4u + hd] + ad;
    e = e > 0.f ? e : NEG_SLOPE * e;
    float ex = __expf(e);
    unsigned v = hb[(unsigned)src * 64u + lane];
    accx += ex * __uint_as_float(v << 16);
    accy += ex * __uint_as_float(v & 0xffff0000u);
    den += ex;
  }
  float inv = 1.0f / (den + 1e-16f);
  unsigned col = hd * 32u + ((unsigned)lane & 15u);
  out[(unsigned)un * 128u + col] = accx * inv + bias[col];
  out[(unsigned)un * 128u + col + 16u] = accy * inv + bias[col + 16];
}

extern "C" void kernel_launch(void* const* d_in, const int* in_sizes, int n_in,
                              void* d_out, int out_size, void* d_ws, size_t ws_size,
                              hipStream_t stream) {
  const float* x    = (const float*)d_in[0];
  const int*   ei   = (const int*)d_in[1];
  const float* W    = (const float*)d_in[2];
  const float* attS = (const float*)d_in[3];
  const float* attD = (const float*)d_in[4];
  const float* bias = (const float*)d_in[5];
  float* out = (float*)d_out;

  const int Nn = in_sizes[0] / 128;
  const int E  = in_sizes[1] / 2;
  const int nb = (Nn + (1 << BSHIFT) - 1) >> BSHIFT;
  const int nbBin = (E + CHUNK - 1) / CHUNK;
  const int nGemm = (Nn + 63) / 64;

  char* ws = (char*)d_ws;
  size_t o = 0;
  auto take = [&](size_t bytes) { void* p = ws + o; o += (bytes + 255) & ~(size_t)255; return p; };
  int* off       = (int*)take((size_t)(Nn + 1) * 4);
  int* ssrc      = (int*)take((size_t)(E + Nn) * 4);
  int* bucketCnt = (int*)take((size_t)NB_MAX * 4);
  int* bucketOff = (int*)take((size_t)(NB_MAX + 1) * 4);
  int* bcur      = (int*)take((size_t)NB_MAX * 4);
  float* aS      = (float*)take((size_t)Nn * 4 * 4);
  float* aD      = (float*)take((size_t)Nn * 4 * 4);
  unsigned short* Wt = (unsigned short*)take((size_t)128 * 128 * 2);
  unsigned int* hb = (unsigned int*)take((size_t)Nn * 64 * 4);
  unsigned int* binned = (unsigned int*)take((size_t)E * 4);  // NOT aliased: concurrent with hb in k_binmm
  (void)ws_size; (void)o;

  hipMemsetAsync(bucketCnt, 0, NB_MAX * 4, stream);
  k_hist_prep<<<nbBin + 64, 256, 0, stream>>>(ei, bucketCnt, E, W, Wt, nbBin);
  k_bucket_scan<<<1, 64, 0, stream>>>(bucketCnt, bucketOff, bcur);
  k_binmm<<<nbBin + nGemm, 256, 0, stream>>>(ei, bcur, binned, E, nb, nbBin,
                                             x, Wt, hb, attS, attD, aS, aD, Nn);
  k_scatter2<<<nb, 256, 0, stream>>>(binned, bucketOff, off, ssrc, Nn, E, nb);
  k_aggregate<<<(Nn + 3) / 4, 256, 0, stream>>>(hb, aS, aD, off, ssrc, bias, out, Nn);
}

// Round 6
// 251.320 us; speedup vs baseline: 2.1455x; 1.0044x over previous
//
#include <hip/hip_runtime.h>

// GAT conv forward: N=100000 nodes, E=1.6M edges (+N self loops), IN_F=128,
// OUT_F=32, HEADS=4. Pipeline (R6, 6 dispatches):
//   1. memset bucketCnt
//   2. k_hist_prep: 256-bucket (dst>>9) edge histogram  +  W->W^T bf16 prep
//   3. k_bucket_scan: 1-wave exclusive scan -> bucketOff/bcur
//   4. k_binmm (fat): blocks [0,nbBin) bin edges (packed src|dstLocal<<20,
//      bucket-id staged as uchar; LDS 23KB -> 6 blocks/CU, was 36KB/4);
//      blocks [nbBin,..) h=x@W mfma bf16 + fused a_src/a_dst epilogue,
//      aS/aD PRESCALED by log2(e) so aggregate uses bare v_exp_f32.
//   5. k_scatter2: per bucket LDS counting-sort -> off[] + coalesced ssrc
//   6. k_aggregate: one wave per dst; scalar (SGPR) indices + saddr gathers,
//      2-deep software pipeline (R5 dropped it when scalarizing -> chunk
//      chain was serial), f32x2 accumulate (v_pk_fma_f32), exp2f.

#define NEG_SLOPE 0.2f
#define NB_MAX 256      // buckets (Nn <= 131072)
#define BSHIFT 9        // 512 nodes per bucket
#define CHUNK 4096      // edges per binning block
#define CAP 11264       // max edges+selfloops per bucket (mean ~8700, 30+ sigma)
#define LOG2E 1.4426950408889634f

typedef __attribute__((ext_vector_type(8))) short short8;
typedef __attribute__((ext_vector_type(4))) float f32x4;
typedef __attribute__((ext_vector_type(2))) float f32x2;

__device__ __forceinline__ unsigned int rne16(unsigned int u) {
  return (u + 0x7fffu + ((u >> 16) & 1u)) >> 16;
}
__device__ __forceinline__ unsigned int f2bf_pack(float a, float b) {
  return (rne16(__float_as_uint(b)) << 16) | (rne16(__float_as_uint(a)) & 0xffffu);
}

// blocks [0,nbBin): bucket histogram; blocks [nbBin,nbBin+64): W^T bf16 prep
__global__ __launch_bounds__(256) void k_hist_prep(
    const int* __restrict__ ei, int* __restrict__ bucketCnt, int E,
    const float* __restrict__ W, unsigned short* __restrict__ Wt, int nbBin) {
  __shared__ int h[NB_MAX];
  int tid = threadIdx.x;
  if ((int)blockIdx.x >= nbBin) {
    int idx = (blockIdx.x - nbBin) * 256 + tid;   // 16384 total
    int k = idx >> 7, col = idx & 127;
    Wt[col * 128 + k] = (unsigned short)rne16(__float_as_uint(W[idx]));
    return;
  }
  h[tid] = 0;
  __syncthreads();
  int base = blockIdx.x * CHUNK;
  int n = E - base; if (n > CHUNK) n = CHUNK;
  for (int i = tid; i < n; i += 256) atomicAdd(&h[ei[E + base + i] >> BSHIFT], 1);
  __syncthreads();
  if (h[tid]) atomicAdd(&bucketCnt[tid], h[tid]);
}

// single wave: exclusive scan of 256 bucket counts -> bucketOff, bcur
__global__ void k_bucket_scan(const int* __restrict__ bucketCnt,
                              int* __restrict__ bucketOff, int* __restrict__ bcur) {
  int lane = threadIdx.x;  // 64
  int base = lane * 4;
  int v0 = bucketCnt[base], v1 = bucketCnt[base + 1];
  int v2 = bucketCnt[base + 2], v3 = bucketCnt[base + 3];
  int s = v0 + v1 + v2 + v3;
  int inc = s;
#pragma unroll
  for (int d = 1; d < 64; d <<= 1) {
    int t = __shfl_up(inc, d, 64);
    if (lane >= d) inc += t;
  }
  int ex = inc - s;
  bucketOff[base] = ex;          bcur[base] = ex;
  bucketOff[base + 1] = ex + v0; bcur[base + 1] = ex + v0;
  bucketOff[base + 2] = ex + v0 + v1; bcur[base + 2] = ex + v0 + v1;
  bucketOff[base + 3] = ex + v0 + v1 + v2; bcur[base + 3] = ex + v0 + v1 + v2;
  if (lane == 63) bucketOff[256] = inc;   // total E
}

// FAT kernel: bin path + gemm(+att) path in one dispatch for overlap.
__global__ __launch_bounds__(256) void k_binmm(
    const int* __restrict__ ei, int* __restrict__ bcur,
    unsigned int* __restrict__ binned, int E, int nb, int nbBin,
    const float* __restrict__ x, const unsigned short* __restrict__ Wt,
    unsigned int* __restrict__ hb,
    const float* __restrict__ attS, const float* __restrict__ attD,
    float* __restrict__ aS, float* __restrict__ aD, int Nn) {
  __shared__ unsigned int buf[CHUNK];     // 16 KB packed src|dstLocal<<20
  __shared__ unsigned char bkt[CHUNK];    // 4 KB bucket id per slot
  __shared__ int hist[NB_MAX];
  __shared__ int loc[NB_MAX];
  __shared__ int gbase[NB_MAX];
  int tid = threadIdx.x;

  if ((int)blockIdx.x < nbBin) {
    // ---------------- bin path ----------------
    int e0 = blockIdx.x * CHUNK;
    int n = E - e0; if (n > CHUNK) n = CHUNK;

    for (int i = tid; i < NB_MAX; i += 256) hist[i] = 0;
    __syncthreads();

    int dstv[CHUNK / 256];
    int rankv[CHUNK / 256];
#pragma unroll
    for (int j = 0; j < CHUNK / 256; ++j) {
      int idx = j * 256 + tid;
      dstv[j] = -1;
      if (idx < n) {
        int d = ei[E + e0 + idx];
        dstv[j] = d;
        rankv[j] = atomicAdd(&hist[d >> BSHIFT], 1);
      }
    }
    __syncthreads();

    if (tid < 64) {
      int base = tid * 4;
      int v0 = hist[base], v1 = hist[base + 1], v2 = hist[base + 2], v3 = hist[base + 3];
      int s = v0 + v1 + v2 + v3;
      int inc = s;
#pragma unroll
      for (int d = 1; d < 64; d <<= 1) {
        int t = __shfl_up(inc, d, 64);
        if (tid >= d) inc += t;
      }
      int ex = inc - s;
      loc[base] = ex; loc[base + 1] = ex + v0;
      loc[base + 2] = ex + v0 + v1; loc[base + 3] = ex + v0 + v1 + v2;
    }
    __syncthreads();

#pragma unroll
    for (int j = 0; j < CHUNK / 256; ++j) {
      if (dstv[j] >= 0) {
        int src = ei[e0 + j * 256 + tid];
        int b = dstv[j] >> BSHIFT;
        int slot = loc[b] + rankv[j];
        buf[slot] = (unsigned)src | ((unsigned)(dstv[j] & 511) << 20);
        bkt[slot] = (unsigned char)b;
      }
    }
    for (int b = tid; b < nb; b += 256)
      if (hist[b] > 0) gbase[b] = atomicAdd(&bcur[b], hist[b]);
    __syncthreads();

    for (int s = tid; s < n; s += 256) {
      int b = bkt[s];
      binned[gbase[b] + (s - loc[b])] = buf[s];
    }
    return;
  }

  // ---------------- gemm + att path ----------------
  int gbid = blockIdx.x - nbBin;
  int w = tid >> 6, lane = tid & 63;
  int m = lane & 15, q = lane >> 4;
  int r0 = gbid * 64 + w * 16;
  int rowA = r0 + m; if (rowA >= Nn) rowA = Nn - 1;
  const float* xrow = x + (unsigned)rowA * 128u;

  f32x4 acc[8];
#pragma unroll
  for (int t = 0; t < 8; ++t) acc[t] = (f32x4){0.f, 0.f, 0.f, 0.f};

#pragma unroll
  for (int ks = 0; ks < 4; ++ks) {
    int k0 = ks * 32 + q * 8;
    float4 a0 = *(const float4*)(xrow + k0);
    float4 a1 = *(const float4*)(xrow + k0 + 4);
    unsigned au[4];
    au[0] = f2bf_pack(a0.x, a0.y);
    au[1] = f2bf_pack(a0.z, a0.w);
    au[2] = f2bf_pack(a1.x, a1.y);
    au[3] = f2bf_pack(a1.z, a1.w);
    short8 af = *(short8*)au;
#pragma unroll
    for (int t = 0; t < 8; ++t) {
      short8 bf = *(const short8*)(Wt + (unsigned)(t * 16 + m) * 128u + k0);
      acc[t] = __builtin_amdgcn_mfma_f32_16x16x32_bf16(af, bf, acc[t], 0, 0, 0);
    }
  }

  // att vector slices owned by this lane: head u cols 32u+m and 32u+m+16
  float sSa[4], sSb[4], sDa[4], sDb[4];
#pragma unroll
  for (int u = 0; u < 4; ++u) {
    sSa[u] = attS[u * 32 + m]; sSb[u] = attS[u * 32 + m + 16];
    sDa[u] = attD[u * 32 + m]; sDb[u] = attD[u * 32 + m + 16];
  }

  // C layout: col = m, row = q*4 + reg
#pragma unroll
  for (int r = 0; r < 4; ++r) {
    int rowo = r0 + q * 4 + r;
    bool ok = rowo < Nn;
    if (ok) {
#pragma unroll
      for (int u = 0; u < 4; ++u)
        hb[(unsigned)rowo * 64u + u * 16 + m] = f2bf_pack(acc[2 * u][r], acc[2 * u + 1][r]);
    }
#pragma unroll
    for (int u = 0; u < 4; ++u) {
      float pS = acc[2 * u][r] * sSa[u] + acc[2 * u + 1][r] * sSb[u];
      float pD = acc[2 * u][r] * sDa[u] + acc[2 * u + 1][r] * sDb[u];
#pragma unroll
      for (int d = 8; d >= 1; d >>= 1) {
        pS += __shfl_down(pS, d, 16);
        pD += __shfl_down(pD, d, 16);
      }
      if (ok && m == 0) {
        aS[(unsigned)rowo * 4u + u] = pS * LOG2E;   // prescale: exp(e)=exp2(e*log2e)
        aD[(unsigned)rowo * 4u + u] = pD * LOG2E;
      }
    }
  }
}

// per bucket: LDS degree count + scan -> off[], counting-sort -> coalesced ssrc
__global__ __launch_bounds__(256) void k_scatter2(
    const unsigned int* __restrict__ binned, const int* __restrict__ bucketOff,
    int* __restrict__ off, int* __restrict__ ssrc, int Nn, int E, int nb) {
  __shared__ int cnt[512];
  __shared__ int loc[512];
  __shared__ int obuf[CAP];
  __shared__ int wsum[4];
  int b = blockIdx.x, tid = threadIdx.x;
  int node0 = b << BSHIFT;
  int nnodes = Nn - node0; if (nnodes > 512) nnodes = 512;
  int base = bucketOff[b];
  int nE = bucketOff[b + 1] - base;

  cnt[tid] = 0; cnt[tid + 256] = 0;
  __syncthreads();
  for (int i = tid; i < nE; i += 256)
    atomicAdd(&cnt[(binned[base + i] >> 20) & 511u], 1);
  __syncthreads();

  int i0 = 2 * tid, i1 = 2 * tid + 1;
  int v0 = cnt[i0] + (i0 < nnodes ? 1 : 0);
  int v1 = cnt[i1] + (i1 < nnodes ? 1 : 0);
  int s = v0 + v1;
  int lane = tid & 63, w = tid >> 6;
  int inc = s;
#pragma unroll
  for (int d = 1; d < 64; d <<= 1) {
    int t = __shfl_up(inc, d, 64);
    if (lane >= d) inc += t;
  }
  if (lane == 63) wsum[w] = inc;
  __syncthreads();
  int wbase = 0;
  for (int ww = 0; ww < w; ++ww) wbase += wsum[ww];
  int ex = wbase + inc - s;
  loc[i0] = ex; loc[i1] = ex + v0;
  __syncthreads();

  int csrBase = base + node0;  // edges before + self loops before
  for (int i = tid; i < nnodes; i += 256) {
    int l = loc[i];
    off[node0 + i] = csrBase + l;
    obuf[l] = node0 + i;       // self loop at segment head
  }
  for (int i = tid; i < 512; i += 256) cnt[i] = loc[i] + 1;
  __syncthreads();

  for (int i = tid; i < nE; i += 256) {
    unsigned p = binned[base + i];
    int d = (p >> 20) & 511u;
    int pos = atomicAdd(&cnt[d], 1);
    if (pos < CAP) obuf[pos] = (int)(p & 0xFFFFFu);
  }
  __syncthreads();

  int tot = nE + nnodes;
  for (int i = tid; i < tot; i += 256) ssrc[csrBase + i] = obuf[i];
  if (b == nb - 1 && tid == 0) off[Nn] = E + Nn;
}

// one wave per dst node; lane l = u*16+c owns cols (32u+c, 32u+c+16), head u.
// Scalar indices (s_load) + saddr gathers + 2-deep software pipeline.
__global__ __launch_bounds__(256) void k_aggregate(
    const unsigned int* __restrict__ hb, const float* __restrict__ aS, const float* __restrict__ aD,
    const int* __restrict__ off, const int* __restrict__ ssrc,
    const float* __restrict__ bias, float* __restrict__ out, int Nn) {
  int wave = threadIdx.x >> 6;
  int lane = threadIdx.x & 63;
  int node = blockIdx.x * 4 + wave;
  if (node >= Nn) return;
  int un = __builtin_amdgcn_readfirstlane(node);   // SGPR: wave-uniform
  unsigned hd = (unsigned)lane >> 4;
  float ad = aD[(unsigned)un * 4u + hd];
  int p0 = off[un], p1 = off[un + 1];              // uniform -> s_load
  const int* sp = ssrc + p0;                       // uniform pointer
  int deg = p1 - p0;
  int nch = deg >> 2;
  f32x2 acc = {0.f, 0.f};
  float denA = 0.f, denB = 0.f;

  int s0 = 0, s1 = 0, s2 = 0, s3 = 0;
  unsigned v0 = 0, v1 = 0, v2 = 0, v3 = 0;
  float a0 = 0.f, a1 = 0.f, a2 = 0.f, a3 = 0.f;
  if (nch > 0) {
    s0 = sp[0]; s1 = sp[1]; s2 = sp[2]; s3 = sp[3];
    v0 = hb[(unsigned)s0 * 64u + lane]; v1 = hb[(unsigned)s1 * 64u + lane];
    v2 = hb[(unsigned)s2 * 64u + lane]; v3 = hb[(unsigned)s3 * 64u + lane];
    a0 = aS[(unsigned)s0 * 4u + hd]; a1 = aS[(unsigned)s1 * 4u + hd];
    a2 = aS[(unsigned)s2 * 4u + hd]; a3 = aS[(unsigned)s3 * 4u + hd];
    sp += 4;
  }
  for (int c = 0; c < nch; ++c) {
    int t0 = 0, t1 = 0, t2 = 0, t3 = 0;
    unsigned w0 = 0, w1 = 0, w2 = 0, w3 = 0;
    float b0 = 0.f, b1 = 0.f, b2 = 0.f, b3 = 0.f;
    if (c + 1 < nch) {   // issue next chunk's loads before current math
      t0 = sp[0]; t1 = sp[1]; t2 = sp[2]; t3 = sp[3];
      w0 = hb[(unsigned)t0 * 64u + lane]; w1 = hb[(unsigned)t1 * 64u + lane];
      w2 = hb[(unsigned)t2 * 64u + lane]; w3 = hb[(unsigned)t3 * 64u + lane];
      b0 = aS[(unsigned)t0 * 4u + hd]; b1 = aS[(unsigned)t1 * 4u + hd];
      b2 = aS[(unsigned)t2 * 4u + hd]; b3 = aS[(unsigned)t3 * 4u + hd];
      sp += 4;
    }
    float e0 = a0 + ad, e1 = a1 + ad, e2 = a2 + ad, e3 = a3 + ad;
    e0 = fmaxf(e0, NEG_SLOPE * e0); e1 = fmaxf(e1, NEG_SLOPE * e1);
    e2 = fmaxf(e2, NEG_SLOPE * e2); e3 = fmaxf(e3, NEG_SLOPE * e3);
    float x0 = exp2f(e0), x1 = exp2f(e1), x2 = exp2f(e2), x3 = exp2f(e3);
    denA += x0 + x1; denB += x2 + x3;
    f32x2 h0 = { __uint_as_float(v0 << 16), __uint_as_float(v0 & 0xffff0000u) };
    f32x2 h1 = { __uint_as_float(v1 << 16), __uint_as_float(v1 & 0xffff0000u) };
    f32x2 h2 = { __uint_as_float(v2 << 16), __uint_as_float(v2 & 0xffff0000u) };
    f32x2 h3 = { __uint_as_float(v3 << 16), __uint_as_float(v3 & 0xffff0000u) };
    acc = h0 * x0 + acc;   // v_pk_fma_f32
    acc = h1 * x1 + acc;
    acc = h2 * x2 + acc;
    acc = h3 * x3 + acc;
    s0 = t0; s1 = t1; s2 = t2; s3 = t3;
    v0 = w0; v1 = w1; v2 = w2; v3 = w3;
    a0 = b0; a1 = b1; a2 = b2; a3 = b3;
  }
  for (int p = nch << 2; p < deg; ++p) {
    int src = (ssrc + p0)[p];                      // uniform -> s_load
    float e = aS[(unsigned)src * 4u + hd] + ad;
    e = fmaxf(e, NEG_SLOPE * e);
    float ex = exp2f(e);
    unsigned v = hb[(unsigned)src * 64u + lane];
    f32x2 hh = { __uint_as_float(v << 16), __uint_as_float(v & 0xffff0000u) };
    acc = hh * ex + acc;
    denA += ex;
  }
  float inv = 1.0f / (denA + denB + 1e-16f);
  unsigned col = hd * 32u + ((unsigned)lane & 15u);
  out[(unsigned)un * 128u + col] = acc.x * inv + bias[col];
  out[(unsigned)un * 128u + col + 16u] = acc.y * inv + bias[col + 16];
}

extern "C" void kernel_launch(void* const* d_in, const int* in_sizes, int n_in,
                              void* d_out, int out_size, void* d_ws, size_t ws_size,
                              hipStream_t stream) {
  const float* x    = (const float*)d_in[0];
  const int*   ei   = (const int*)d_in[1];
  const float* W    = (const float*)d_in[2];
  const float* attS = (const float*)d_in[3];
  const float* attD = (const float*)d_in[4];
  const float* bias = (const float*)d_in[5];
  float* out = (float*)d_out;

  const int Nn = in_sizes[0] / 128;
  const int E  = in_sizes[1] / 2;
  const int nb = (Nn + (1 << BSHIFT) - 1) >> BSHIFT;
  const int nbBin = (E + CHUNK - 1) / CHUNK;
  const int nGemm = (Nn + 63) / 64;

  char* ws = (char*)d_ws;
  size_t o = 0;
  auto take = [&](size_t bytes) { void* p = ws + o; o += (bytes + 255) & ~(size_t)255; return p; };
  int* off       = (int*)take((size_t)(Nn + 1) * 4);
  int* ssrc      = (int*)take((size_t)(E + Nn) * 4);
  int* bucketCnt = (int*)take((size_t)NB_MAX * 4);
  int* bucketOff = (int*)take((size_t)(NB_MAX + 1) * 4);
  int* bcur      = (int*)take((size_t)NB_MAX * 4);
  float* aS      = (float*)take((size_t)Nn * 4 * 4);
  float* aD      = (float*)take((size_t)Nn * 4 * 4);
  unsigned short* Wt = (unsigned short*)take((size_t)128 * 128 * 2);
  unsigned int* hb = (unsigned int*)take((size_t)Nn * 64 * 4);
  unsigned int* binned = (unsigned int*)take((size_t)E * 4);  // NOT aliased: concurrent with hb in k_binmm
  (void)ws_size; (void)o;

  hipMemsetAsync(bucketCnt, 0, NB_MAX * 4, stream);
  k_hist_prep<<<nbBin + 64, 256, 0, stream>>>(ei, bucketCnt, E, W, Wt, nbBin);
  k_bucket_scan<<<1, 64, 0, stream>>>(bucketCnt, bucketOff, bcur);
  k_binmm<<<nbBin + nGemm, 256, 0, stream>>>(ei, bcur, binned, E, nb, nbBin,
                                             x, Wt, hb, attS, attD, aS, aD, Nn);
  k_scatter2<<<nb, 256, 0, stream>>>(binned, bucketOff, off, ssrc, Nn, E, nb);
  k_aggregate<<<(Nn + 3) / 4, 256, 0, stream>>>(hb, aS, aD, off, ssrc, bias, out, Nn);
}